// Round 2
// baseline (3000.465 us; speedup 1.0000x reference)
//
#include <hip/hip_runtime.h>
#include <math.h>

#define D 128
#define NBUCK_MAX 1024     // runtime nbuck = ceil(N/128) = 782
#define NB_EDGE   128      // edge-chunk blocks for count/placement passes

// ---------------- bucketed edge grouping (atomic-free global placement) ----------------

// Pass 1: per-block LDS histogram of dst buckets.
__global__ __launch_bounds__(512) void bucket_count(const int* __restrict__ dst, int E, int nbuck,
                                                    int* __restrict__ blockHist) {
    __shared__ int h[NBUCK_MAX];
    int tid = threadIdx.x;
    for (int i = tid; i < nbuck; i += 512) h[i] = 0;
    __syncthreads();
    int per = (E + NB_EDGE - 1) / NB_EDGE;
    int s = blockIdx.x * per, e = min(E, s + per);
    for (int i = s + tid; i < e; i += 512) atomicAdd(&h[dst[i] >> 7], 1);
    __syncthreads();
    for (int i = tid; i < nbuck; i += 512) blockHist[blockIdx.x * nbuck + i] = h[i];
}

// Pass 2a: for each bucket, exclusive-scan its 128 per-block counts (one wave per bucket).
__global__ __launch_bounds__(256) void scan_blocks(int* __restrict__ blockHist, int nbuck,
                                                   int* __restrict__ bucketTotal) {
    int bucket = (blockIdx.x * 256 + threadIdx.x) >> 6;
    int lane = threadIdx.x & 63;
    if (bucket >= nbuck) return;
    int v0 = blockHist[lane * nbuck + bucket];
    int v1 = blockHist[(lane + 64) * nbuck + bucket];
    int i0 = v0;
    #pragma unroll
    for (int off = 1; off < 64; off <<= 1) { int t = __shfl_up(i0, off); if (lane >= off) i0 += t; }
    int tot0 = __shfl(i0, 63);
    int i1 = v1;
    #pragma unroll
    for (int off = 1; off < 64; off <<= 1) { int t = __shfl_up(i1, off); if (lane >= off) i1 += t; }
    i1 += tot0;
    blockHist[lane * nbuck + bucket] = i0 - v0;
    blockHist[(lane + 64) * nbuck + bucket] = i1 - v1;
    if (lane == 63) bucketTotal[bucket] = i1;
}

// Pass 2b: single-block exclusive scan of bucket totals -> bucketBase[0..nbuck] (sentinel at nbuck).
__global__ __launch_bounds__(256) void scan_buckets(const int* __restrict__ bucketTotal, int nbuck,
                                                    int* __restrict__ bucketBase) {
    __shared__ int wsum[4];
    int tid = threadIdx.x;
    int base = tid * 4;
    int v[4];
    #pragma unroll
    for (int k = 0; k < 4; k++) v[k] = (base + k < nbuck) ? bucketTotal[base + k] : 0;
    int s = v[0] + v[1] + v[2] + v[3];
    int lane = tid & 63;
    int incl = s;
    #pragma unroll
    for (int off = 1; off < 64; off <<= 1) { int t = __shfl_up(incl, off); if (lane >= off) incl += t; }
    int wv = tid >> 6;
    if (lane == 63) wsum[wv] = incl;
    __syncthreads();
    int woff = 0;
    for (int w = 0; w < wv; w++) woff += wsum[w];
    int excl = woff + incl - s;
    int run = excl;
    #pragma unroll
    for (int k = 0; k < 4; k++) {
        if (base + k <= nbuck) bucketBase[base + k] = run;
        run += v[k];
    }
}

// Pass 3: deterministic placement via LDS cursors; packed edge = src | (dstLocal << 20).
__global__ __launch_bounds__(512) void bucket_place(const int* __restrict__ src, const int* __restrict__ dst,
                                                    int E, int nbuck, const int* __restrict__ blockHist,
                                                    const int* __restrict__ bucketBase,
                                                    unsigned int* __restrict__ edgeBuf) {
    __shared__ int cur[NBUCK_MAX];
    int tid = threadIdx.x;
    for (int i = tid; i < nbuck; i += 512)
        cur[i] = bucketBase[i] + blockHist[blockIdx.x * nbuck + i];
    __syncthreads();
    int per = (E + NB_EDGE - 1) / NB_EDGE;
    int s = blockIdx.x * per, e = min(E, s + per);
    for (int i = s + tid; i < e; i += 512) {
        int d = dst[i];
        int b = d >> 7;
        int pos = atomicAdd(&cur[b], 1);
        edgeBuf[pos] = (unsigned int)src[i] | ((unsigned int)(d & 127) << 20);
    }
}

// exclusive scan of graph sizes (G <= 1024), single block of 256
__global__ __launch_bounds__(256) void goff_scan(const int* __restrict__ gsz, int G, int* __restrict__ goff) {
    __shared__ int wsum[4];
    int tid = threadIdx.x;
    int base = tid * 4;
    int a = base + 0 < G ? gsz[base + 0] : 0;
    int b = base + 1 < G ? gsz[base + 1] : 0;
    int c = base + 2 < G ? gsz[base + 2] : 0;
    int d = base + 3 < G ? gsz[base + 3] : 0;
    int s = a + b + c + d;
    int lane = tid & 63;
    int incl = s;
    #pragma unroll
    for (int off = 1; off < 64; off <<= 1) { int t = __shfl_up(incl, off); if (lane >= off) incl += t; }
    int wv = tid >> 6;
    if (lane == 63) wsum[wv] = incl;
    __syncthreads();
    int woff = 0;
    for (int w = 0; w < wv; w++) woff += wsum[w];
    int excl = woff + incl - s;
    if (base + 0 < G) goff[base + 0] = excl;
    if (base + 1 < G) goff[base + 1] = excl + a;
    if (base + 2 < G) goff[base + 2] = excl + a + b;
    if (base + 3 < G) goff[base + 3] = excl + a + b + c;
}

// ---------------- dense GEMM: out[N][128] = A[N][128] @ W[128][128] ----------------
__global__ __launch_bounds__(256, 2) void gemm128(const float* __restrict__ A, const float* __restrict__ W,
                                                  float* __restrict__ out, int N) {
    __shared__ float Xs[64 * 128];
    __shared__ float Ws[128 * 64];
    const int tid = threadIdx.x;
    const int row0 = blockIdx.x * 64;
    const int c0 = blockIdx.y * 64;
    for (int i = tid; i < 128 * 16; i += 256) {
        int k = i >> 4;
        int c4 = (i & 15) * 4;
        *(float4*)(Ws + k * 64 + c4) = *(const float4*)(W + k * 128 + c0 + c4);
    }
    for (int i = tid; i < 64 * 32; i += 256) {
        int r = i >> 5;
        int k4 = (i & 31) * 4;
        int gr = row0 + r;
        float4 v = make_float4(0.f, 0.f, 0.f, 0.f);
        if (gr < N) v = *(const float4*)(A + gr * 128 + k4);
        *(float4*)(Xs + r * 128 + k4) = v;
    }
    __syncthreads();
    const int tx = tid & 15;
    const int ty = tid >> 4;
    const int rbase = ty * 4;
    const int cbase = tx * 4;
    float acc[4][4] = {};
    #pragma unroll 4
    for (int k = 0; k < 128; k += 4) {
        float4 xv[4], wv[4];
        #pragma unroll
        for (int r = 0; r < 4; r++) xv[r] = *(const float4*)(Xs + (rbase + r) * 128 + k);
        #pragma unroll
        for (int kk = 0; kk < 4; kk++) wv[kk] = *(const float4*)(Ws + (k + kk) * 64 + cbase);
        #pragma unroll
        for (int r = 0; r < 4; r++) {
            const float* xr = (const float*)&xv[r];
            #pragma unroll
            for (int kk = 0; kk < 4; kk++) {
                float x = xr[kk];
                acc[r][0] += x * wv[kk].x;
                acc[r][1] += x * wv[kk].y;
                acc[r][2] += x * wv[kk].z;
                acc[r][3] += x * wv[kk].w;
            }
        }
    }
    #pragma unroll
    for (int r = 0; r < 4; r++) {
        int gr = row0 + rbase + r;
        if (gr < N)
            *(float4*)(out + gr * 128 + c0 + cbase) =
                make_float4(acc[r][0], acc[r][1], acc[r][2], acc[r][3]);
    }
}

// ---------------- bucketed aggregate: block per bucket of 128 nodes ----------------
// acc[128][128] in LDS (64 KiB -> 2 blocks/CU). Waves gather xw[src] (float2/lane) and
// LDS-atomic-add into the dst slot; then self term + bias + relu + coalesced store.
__global__ __launch_bounds__(256, 2) void agg_bucket(const float* __restrict__ xw,
                                                     const int* __restrict__ bucketBase,
                                                     const unsigned int* __restrict__ edgeBuf,
                                                     const float* __restrict__ bias,
                                                     float* __restrict__ outp, int N) {
    __shared__ float acc[128 * 128];
    const int tid = threadIdx.x;
    const int wid = tid >> 6;
    const int lane = tid & 63;
    const int c2 = lane * 2;
    float4 z = make_float4(0.f, 0.f, 0.f, 0.f);
    for (int i = tid; i < 128 * 32; i += 256) ((float4*)acc)[i] = z;
    __syncthreads();
    const int start = bucketBase[blockIdx.x];
    const int end = bucketBase[blockIdx.x + 1];
    for (int s = start + wid * 64; s < end; s += 256) {
        int cnt = min(64, end - s);
        unsigned int p = (lane < cnt) ? edgeBuf[s + lane] : 0u;
        int i = 0;
        for (; i + 3 < cnt; i += 4) {
            unsigned int p0 = __shfl(p, i), p1 = __shfl(p, i + 1);
            unsigned int p2 = __shfl(p, i + 2), p3 = __shfl(p, i + 3);
            float2 v0 = *(const float2*)(xw + (p0 & 0xFFFFFu) * D + c2);
            float2 v1 = *(const float2*)(xw + (p1 & 0xFFFFFu) * D + c2);
            float2 v2 = *(const float2*)(xw + (p2 & 0xFFFFFu) * D + c2);
            float2 v3 = *(const float2*)(xw + (p3 & 0xFFFFFu) * D + c2);
            int d0 = (int)(p0 >> 20) * D + c2;
            int d1 = (int)(p1 >> 20) * D + c2;
            int d2 = (int)(p2 >> 20) * D + c2;
            int d3 = (int)(p3 >> 20) * D + c2;
            atomicAdd(&acc[d0], v0.x); atomicAdd(&acc[d0 + 1], v0.y);
            atomicAdd(&acc[d1], v1.x); atomicAdd(&acc[d1 + 1], v1.y);
            atomicAdd(&acc[d2], v2.x); atomicAdd(&acc[d2 + 1], v2.y);
            atomicAdd(&acc[d3], v3.x); atomicAdd(&acc[d3 + 1], v3.y);
        }
        for (; i < cnt; i++) {
            unsigned int p0 = __shfl(p, i);
            float2 v0 = *(const float2*)(xw + (p0 & 0xFFFFFu) * D + c2);
            int d0 = (int)(p0 >> 20) * D + c2;
            atomicAdd(&acc[d0], v0.x); atomicAdd(&acc[d0 + 1], v0.y);
        }
    }
    __syncthreads();
    const int node0 = blockIdx.x * 128;
    float2 b = *(const float2*)(bias + c2);
    for (int n = wid; n < 128; n += 4) {
        int node = node0 + n;
        if (node >= N) break;
        float2 a = *(const float2*)(acc + n * D + c2);
        float2 x = *(const float2*)(xw + node * D + c2);
        float2 r = make_float2(fmaxf(a.x + x.x + b.x, 0.f), fmaxf(a.y + x.y + b.y, 0.f));
        *(float2*)(outp + node * D + c2) = r;
    }
}

// ---------------- head: out12[n][12] = sigmoid(h[n] @ Wf + bf) ----------------
__global__ __launch_bounds__(256) void head_sigmoid(const float* __restrict__ h, const float* __restrict__ Wf,
                                                    const float* __restrict__ bfv, float* __restrict__ out12, int N) {
    __shared__ float Wl[128 * 12];
    __shared__ float bl[12];
    for (int i = threadIdx.x; i < 128 * 12; i += 256) Wl[i] = Wf[i];
    if (threadIdx.x < 12) bl[threadIdx.x] = bfv[threadIdx.x];
    __syncthreads();
    int node = blockIdx.x * 256 + threadIdx.x;
    if (node >= N) return;
    float acc[12];
    #pragma unroll
    for (int t = 0; t < 12; t++) acc[t] = bl[t];
    const float* hr = h + (size_t)node * D;
    for (int k = 0; k < 128; k += 4) {
        float4 hv = *(const float4*)(hr + k);
        const float* hx = (const float*)&hv;
        #pragma unroll
        for (int kk = 0; kk < 4; kk++) {
            float x = hx[kk];
            const float* wr = Wl + (k + kk) * 12;
            #pragma unroll
            for (int t = 0; t < 12; t++) acc[t] += x * wr[t];
        }
    }
    float* o = out12 + (size_t)node * 12;
    #pragma unroll
    for (int t = 0; t < 12; t++) o[t] = 1.f / (1.f + __expf(-acc[t]));
}

// ---------------- per-graph mean ----------------
__global__ __launch_bounds__(128) void graph_mean(const float* __restrict__ out12, const int* __restrict__ goff,
                                                  const int* __restrict__ gsize, float* __restrict__ out, int G) {
    __shared__ float partial[120];
    int g = blockIdx.x;
    int tid = threadIdx.x;
    int start = goff[g];
    int size = gsize[g];
    if (tid < 120) {
        int t = tid % 12, chunk = tid / 12;
        float s = 0.f;
        for (int i = chunk; i < size; i += 10)
            s += out12[(size_t)(start + i) * 12 + t];
        partial[tid] = s;
    }
    __syncthreads();
    if (tid < 12) {
        float tot = 0.f;
        #pragma unroll
        for (int c = 0; c < 10; c++) tot += partial[c * 12 + tid];
        out[g * 12 + tid] = tot / (float)size;
    }
}

// ---------------- launch ----------------

extern "C" void kernel_launch(void* const* d_in, const int* in_sizes, int n_in,
                              void* d_out, int out_size, void* d_ws, size_t ws_size,
                              hipStream_t stream) {
    const float* X   = (const float*)d_in[0];
    const int* edges = (const int*)d_in[1];
    const int* gsz   = (const int*)d_in[2];
    const float* W0  = (const float*)d_in[3];
    const float* b0  = (const float*)d_in[4];
    const float* W1  = (const float*)d_in[5];
    const float* b1  = (const float*)d_in[6];
    const float* Wf  = (const float*)d_in[7];
    const float* bfv = (const float*)d_in[8];
    float* out = (float*)d_out;

    const int N = in_sizes[0] / D;       // 100000
    const int E = in_sizes[1] / 2;       // 1600000
    const int G = in_sizes[2];           // 1000
    const int* esrc = edges;
    const int* edst = edges + E;
    const int nbuck = (N + 127) >> 7;    // 782

    // workspace layout
    char* ws = (char*)d_ws;
    float* xw    = (float*)(ws);                                  // N*128 f32
    float* hbuf  = (float*)(ws + (size_t)N * D * 4);              // N*128 f32
    float* out12 = (float*)(ws + (size_t)2 * N * D * 4);          // N*12 f32
    char* p = ws + (size_t)2 * N * D * 4 + (((size_t)N * 12 * 4 + 255) & ~255ull);
    unsigned int* edgeBuf = (unsigned int*)p;  p += (((size_t)E * 4) + 255) & ~255ull;
    int* blockHist   = (int*)p;                p += ((size_t)NB_EDGE * NBUCK_MAX * 4 + 255) & ~255ull;
    int* bucketTotal = (int*)p;                p += ((size_t)NBUCK_MAX * 4 + 255) & ~255ull;
    int* bucketBase  = (int*)p;                p += ((size_t)(NBUCK_MAX + 1) * 4 + 255) & ~255ull;
    int* goff        = (int*)p;

    // edge grouping (atomic-free global placement)
    bucket_count<<<NB_EDGE, 512, 0, stream>>>(edst, E, nbuck, blockHist);
    scan_blocks<<<(nbuck * 64 + 255) / 256, 256, 0, stream>>>(blockHist, nbuck, bucketTotal);
    scan_buckets<<<1, 256, 0, stream>>>(bucketTotal, nbuck, bucketBase);
    bucket_place<<<NB_EDGE, 512, 0, stream>>>(esrc, edst, E, nbuck, blockHist, bucketBase, edgeBuf);

    // graph offsets
    goff_scan<<<1, 256, 0, stream>>>(gsz, G, goff);

    dim3 ggrid((N + 63) / 64, 2);
    // layer 0
    gemm128<<<ggrid, 256, 0, stream>>>(X, W0, xw, N);
    agg_bucket<<<nbuck, 256, 0, stream>>>(xw, bucketBase, edgeBuf, b0, hbuf, N);
    // layer 1
    gemm128<<<ggrid, 256, 0, stream>>>(hbuf, W1, xw, N);
    agg_bucket<<<nbuck, 256, 0, stream>>>(xw, bucketBase, edgeBuf, b1, hbuf, N);
    // head + readout
    head_sigmoid<<<(N + 255) / 256, 256, 0, stream>>>(hbuf, Wf, bfv, out12, N);
    graph_mean<<<G, 128, 0, stream>>>(out12, goff, gsz, out, G);
}

// Round 3
// 554.925 us; speedup vs baseline: 5.4070x; 5.4070x over previous
//
#include <hip/hip_runtime.h>
#include <math.h>

#define D 128
#define NBUCK_MAX 1024     // runtime nbuck = ceil(N/128) = 782
#define NB_EDGE   128      // edge-chunk blocks for count/placement passes

// ---------------- bucketed edge grouping (atomic-free global placement) ----------------

// Pass 1: per-block LDS histogram of dst buckets (bucket = dst >> 7).
__global__ __launch_bounds__(512) void bucket_count(const int* __restrict__ dst, int E, int nbuck,
                                                    int* __restrict__ blockHist) {
    __shared__ int h[NBUCK_MAX];
    int tid = threadIdx.x;
    for (int i = tid; i < nbuck; i += 512) h[i] = 0;
    __syncthreads();
    int per = (E + NB_EDGE - 1) / NB_EDGE;
    int s = blockIdx.x * per, e = min(E, s + per);
    for (int i = s + tid; i < e; i += 512) atomicAdd(&h[dst[i] >> 7], 1);
    __syncthreads();
    for (int i = tid; i < nbuck; i += 512) blockHist[blockIdx.x * nbuck + i] = h[i];
}

// Pass 2a: for each bucket, exclusive-scan its 128 per-block counts (one wave per bucket).
__global__ __launch_bounds__(256) void scan_blocks(int* __restrict__ blockHist, int nbuck,
                                                   int* __restrict__ bucketTotal) {
    int bucket = (blockIdx.x * 256 + threadIdx.x) >> 6;
    int lane = threadIdx.x & 63;
    if (bucket >= nbuck) return;
    int v0 = blockHist[lane * nbuck + bucket];
    int v1 = blockHist[(lane + 64) * nbuck + bucket];
    int i0 = v0;
    #pragma unroll
    for (int off = 1; off < 64; off <<= 1) { int t = __shfl_up(i0, off); if (lane >= off) i0 += t; }
    int tot0 = __shfl(i0, 63);
    int i1 = v1;
    #pragma unroll
    for (int off = 1; off < 64; off <<= 1) { int t = __shfl_up(i1, off); if (lane >= off) i1 += t; }
    i1 += tot0;
    blockHist[lane * nbuck + bucket] = i0 - v0;
    blockHist[(lane + 64) * nbuck + bucket] = i1 - v1;
    if (lane == 63) bucketTotal[bucket] = i1;
}

// Pass 2b: single-block exclusive scan of bucket totals -> bucketBase[0..nbuck] (sentinel).
__global__ __launch_bounds__(256) void scan_buckets(const int* __restrict__ bucketTotal, int nbuck,
                                                    int* __restrict__ bucketBase) {
    __shared__ int wsum[4];
    int tid = threadIdx.x;
    int base = tid * 4;
    int v[4];
    #pragma unroll
    for (int k = 0; k < 4; k++) v[k] = (base + k < nbuck) ? bucketTotal[base + k] : 0;
    int s = v[0] + v[1] + v[2] + v[3];
    int lane = tid & 63;
    int incl = s;
    #pragma unroll
    for (int off = 1; off < 64; off <<= 1) { int t = __shfl_up(incl, off); if (lane >= off) incl += t; }
    int wv = tid >> 6;
    if (lane == 63) wsum[wv] = incl;
    __syncthreads();
    int woff = 0;
    for (int w = 0; w < wv; w++) woff += wsum[w];
    int excl = woff + incl - s;
    int run = excl;
    #pragma unroll
    for (int k = 0; k < 4; k++) {
        if (base + k <= nbuck) bucketBase[base + k] = run;
        run += v[k];
    }
}

// Pass 3: deterministic placement via LDS cursors; packed edge = src | (dstLocal << 20).
__global__ __launch_bounds__(512) void bucket_place(const int* __restrict__ src, const int* __restrict__ dst,
                                                    int E, int nbuck, const int* __restrict__ blockHist,
                                                    const int* __restrict__ bucketBase,
                                                    unsigned int* __restrict__ edgeBuf) {
    __shared__ int cur[NBUCK_MAX];
    int tid = threadIdx.x;
    for (int i = tid; i < nbuck; i += 512)
        cur[i] = bucketBase[i] + blockHist[blockIdx.x * nbuck + i];
    __syncthreads();
    int per = (E + NB_EDGE - 1) / NB_EDGE;
    int s = blockIdx.x * per, e = min(E, s + per);
    for (int i = s + tid; i < e; i += 512) {
        int d = dst[i];
        int b = d >> 7;
        int pos = atomicAdd(&cur[b], 1);
        edgeBuf[pos] = (unsigned int)src[i] | ((unsigned int)(d & 127) << 20);
    }
}

// Pass 4: per-bucket LDS counting sort -> global per-node CSR (row_ptr + col_idx).
__global__ __launch_bounds__(256) void csr_finalize(const unsigned int* __restrict__ edgeBuf,
                                                    const int* __restrict__ bucketBase,
                                                    int* __restrict__ row_ptr, int* __restrict__ col_idx,
                                                    int N, int E) {
    __shared__ int hist[128];
    __shared__ int cursor[128];
    int b = blockIdx.x;
    int tid = threadIdx.x;
    int start = bucketBase[b], end = bucketBase[b + 1];
    if (tid < 128) hist[tid] = 0;
    __syncthreads();
    for (int i = start + tid; i < end; i += 256)
        atomicAdd(&hist[edgeBuf[i] >> 20], 1);
    __syncthreads();
    if (tid < 64) {   // wave 0: scan 128 bins, 2 per lane
        int v0 = hist[tid * 2], v1 = hist[tid * 2 + 1];
        int s = v0 + v1;
        int incl = s;
        #pragma unroll
        for (int off = 1; off < 64; off <<= 1) { int t = __shfl_up(incl, off); if (tid >= off) incl += t; }
        int excl = incl - s;
        cursor[tid * 2] = excl;
        cursor[tid * 2 + 1] = excl + v0;
        int node = b * 128 + tid * 2;
        if (node < N) row_ptr[node] = start + excl;
        if (node + 1 < N) row_ptr[node + 1] = start + excl + v0;
    }
    __syncthreads();
    for (int i = start + tid; i < end; i += 256) {
        unsigned int p = edgeBuf[i];
        int pos = atomicAdd(&cursor[p >> 20], 1);
        col_idx[start + pos] = (int)(p & 0xFFFFFu);
    }
    if (b == 0 && tid == 0) row_ptr[N] = E;
}

// exclusive scan of graph sizes (G <= 1024), single block of 256
__global__ __launch_bounds__(256) void goff_scan(const int* __restrict__ gsz, int G, int* __restrict__ goff) {
    __shared__ int wsum[4];
    int tid = threadIdx.x;
    int base = tid * 4;
    int a = base + 0 < G ? gsz[base + 0] : 0;
    int b = base + 1 < G ? gsz[base + 1] : 0;
    int c = base + 2 < G ? gsz[base + 2] : 0;
    int d = base + 3 < G ? gsz[base + 3] : 0;
    int s = a + b + c + d;
    int lane = tid & 63;
    int incl = s;
    #pragma unroll
    for (int off = 1; off < 64; off <<= 1) { int t = __shfl_up(incl, off); if (lane >= off) incl += t; }
    int wv = tid >> 6;
    if (lane == 63) wsum[wv] = incl;
    __syncthreads();
    int woff = 0;
    for (int w = 0; w < wv; w++) woff += wsum[w];
    int excl = woff + incl - s;
    if (base + 0 < G) goff[base + 0] = excl;
    if (base + 1 < G) goff[base + 1] = excl + a;
    if (base + 2 < G) goff[base + 2] = excl + a + b;
    if (base + 3 < G) goff[base + 3] = excl + a + b + c;
}

// ---------------- dense GEMM: out[N][128] = A[N][128] @ W[128][128] ----------------
__global__ __launch_bounds__(256, 2) void gemm128(const float* __restrict__ A, const float* __restrict__ W,
                                                  float* __restrict__ out, int N) {
    __shared__ float Xs[64 * 128];
    __shared__ float Ws[128 * 64];
    const int tid = threadIdx.x;
    const int row0 = blockIdx.x * 64;
    const int c0 = blockIdx.y * 64;
    for (int i = tid; i < 128 * 16; i += 256) {
        int k = i >> 4;
        int c4 = (i & 15) * 4;
        *(float4*)(Ws + k * 64 + c4) = *(const float4*)(W + k * 128 + c0 + c4);
    }
    for (int i = tid; i < 64 * 32; i += 256) {
        int r = i >> 5;
        int k4 = (i & 31) * 4;
        int gr = row0 + r;
        float4 v = make_float4(0.f, 0.f, 0.f, 0.f);
        if (gr < N) v = *(const float4*)(A + gr * 128 + k4);
        *(float4*)(Xs + r * 128 + k4) = v;
    }
    __syncthreads();
    const int tx = tid & 15;
    const int ty = tid >> 4;
    const int rbase = ty * 4;
    const int cbase = tx * 4;
    float acc[4][4] = {};
    #pragma unroll 4
    for (int k = 0; k < 128; k += 4) {
        float4 xv[4], wv[4];
        #pragma unroll
        for (int r = 0; r < 4; r++) xv[r] = *(const float4*)(Xs + (rbase + r) * 128 + k);
        #pragma unroll
        for (int kk = 0; kk < 4; kk++) wv[kk] = *(const float4*)(Ws + (k + kk) * 64 + cbase);
        #pragma unroll
        for (int r = 0; r < 4; r++) {
            const float* xr = (const float*)&xv[r];
            #pragma unroll
            for (int kk = 0; kk < 4; kk++) {
                float x = xr[kk];
                acc[r][0] += x * wv[kk].x;
                acc[r][1] += x * wv[kk].y;
                acc[r][2] += x * wv[kk].z;
                acc[r][3] += x * wv[kk].w;
            }
        }
    }
    #pragma unroll
    for (int r = 0; r < 4; r++) {
        int gr = row0 + rbase + r;
        if (gr < N)
            *(float4*)(out + gr * 128 + c0 + cbase) =
                make_float4(acc[r][0], acc[r][1], acc[r][2], acc[r][3]);
    }
}

// ---------------- aggregate: out[i] = relu(xw[i] + b + sum_{j in CSR[i]} xw[j]) ----------------
// one wave per node; lane holds float2 slice; 8 gathers in flight per iteration.
__global__ __launch_bounds__(256) void agg_relu(const float* __restrict__ xw, const int* __restrict__ row_ptr,
                                                const int* __restrict__ col_idx, const float* __restrict__ bias,
                                                float* __restrict__ outp, int N) {
    int wid = (blockIdx.x * 256 + threadIdx.x) >> 6;
    int lane = threadIdx.x & 63;
    if (wid >= N) return;
    const int c2 = lane * 2;
    float2 b = *(const float2*)(bias + c2);
    float2 self = *(const float2*)(xw + (size_t)wid * D + c2);
    float2 acc = make_float2(self.x + b.x, self.y + b.y);
    int start = row_ptr[wid], end = row_ptr[wid + 1];
    for (int e = start; e < end; e += 64) {
        int idx = e + lane;
        int j = (idx < end) ? col_idx[idx] : 0;
        int cnt = min(64, end - e);
        int i = 0;
        for (; i + 7 < cnt; i += 8) {
            int j0 = __shfl(j, i),     j1 = __shfl(j, i + 1);
            int j2 = __shfl(j, i + 2), j3 = __shfl(j, i + 3);
            int j4 = __shfl(j, i + 4), j5 = __shfl(j, i + 5);
            int j6 = __shfl(j, i + 6), j7 = __shfl(j, i + 7);
            float2 v0 = *(const float2*)(xw + (size_t)j0 * D + c2);
            float2 v1 = *(const float2*)(xw + (size_t)j1 * D + c2);
            float2 v2 = *(const float2*)(xw + (size_t)j2 * D + c2);
            float2 v3 = *(const float2*)(xw + (size_t)j3 * D + c2);
            float2 v4 = *(const float2*)(xw + (size_t)j4 * D + c2);
            float2 v5 = *(const float2*)(xw + (size_t)j5 * D + c2);
            float2 v6 = *(const float2*)(xw + (size_t)j6 * D + c2);
            float2 v7 = *(const float2*)(xw + (size_t)j7 * D + c2);
            acc.x += ((v0.x + v1.x) + (v2.x + v3.x)) + ((v4.x + v5.x) + (v6.x + v7.x));
            acc.y += ((v0.y + v1.y) + (v2.y + v3.y)) + ((v4.y + v5.y) + (v6.y + v7.y));
        }
        for (; i < cnt; i++) {
            int j0 = __shfl(j, i);
            float2 v0 = *(const float2*)(xw + (size_t)j0 * D + c2);
            acc.x += v0.x;
            acc.y += v0.y;
        }
    }
    acc.x = fmaxf(acc.x, 0.f);
    acc.y = fmaxf(acc.y, 0.f);
    *(float2*)(outp + (size_t)wid * D + c2) = acc;
}

// ---------------- head: out12[n][12] = sigmoid(h[n] @ Wf + bf) ----------------
__global__ __launch_bounds__(256) void head_sigmoid(const float* __restrict__ h, const float* __restrict__ Wf,
                                                    const float* __restrict__ bfv, float* __restrict__ out12, int N) {
    __shared__ float Wl[128 * 12];
    __shared__ float bl[12];
    for (int i = threadIdx.x; i < 128 * 12; i += 256) Wl[i] = Wf[i];
    if (threadIdx.x < 12) bl[threadIdx.x] = bfv[threadIdx.x];
    __syncthreads();
    int node = blockIdx.x * 256 + threadIdx.x;
    if (node >= N) return;
    float acc[12];
    #pragma unroll
    for (int t = 0; t < 12; t++) acc[t] = bl[t];
    const float* hr = h + (size_t)node * D;
    for (int k = 0; k < 128; k += 4) {
        float4 hv = *(const float4*)(hr + k);
        const float* hx = (const float*)&hv;
        #pragma unroll
        for (int kk = 0; kk < 4; kk++) {
            float x = hx[kk];
            const float* wr = Wl + (k + kk) * 12;
            #pragma unroll
            for (int t = 0; t < 12; t++) acc[t] += x * wr[t];
        }
    }
    float* o = out12 + (size_t)node * 12;
    #pragma unroll
    for (int t = 0; t < 12; t++) o[t] = 1.f / (1.f + __expf(-acc[t]));
}

// ---------------- per-graph mean ----------------
__global__ __launch_bounds__(128) void graph_mean(const float* __restrict__ out12, const int* __restrict__ goff,
                                                  const int* __restrict__ gsize, float* __restrict__ out, int G) {
    __shared__ float partial[120];
    int g = blockIdx.x;
    int tid = threadIdx.x;
    int start = goff[g];
    int size = gsize[g];
    if (tid < 120) {
        int t = tid % 12, chunk = tid / 12;
        float s = 0.f;
        for (int i = chunk; i < size; i += 10)
            s += out12[(size_t)(start + i) * 12 + t];
        partial[tid] = s;
    }
    __syncthreads();
    if (tid < 12) {
        float tot = 0.f;
        #pragma unroll
        for (int c = 0; c < 10; c++) tot += partial[c * 12 + tid];
        out[g * 12 + tid] = tot / (float)size;
    }
}

// ---------------- launch ----------------

extern "C" void kernel_launch(void* const* d_in, const int* in_sizes, int n_in,
                              void* d_out, int out_size, void* d_ws, size_t ws_size,
                              hipStream_t stream) {
    const float* X   = (const float*)d_in[0];
    const int* edges = (const int*)d_in[1];
    const int* gsz   = (const int*)d_in[2];
    const float* W0  = (const float*)d_in[3];
    const float* b0  = (const float*)d_in[4];
    const float* W1  = (const float*)d_in[5];
    const float* b1  = (const float*)d_in[6];
    const float* Wf  = (const float*)d_in[7];
    const float* bfv = (const float*)d_in[8];
    float* out = (float*)d_out;

    const int N = in_sizes[0] / D;       // 100000
    const int E = in_sizes[1] / 2;       // 1600000
    const int G = in_sizes[2];           // 1000
    const int* esrc = edges;
    const int* edst = edges + E;
    const int nbuck = (N + 127) >> 7;    // 782

    // workspace layout
    char* ws = (char*)d_ws;
    float* xw    = (float*)(ws);                                  // N*128 f32
    float* hbuf  = (float*)(ws + (size_t)N * D * 4);              // N*128 f32
    float* out12 = (float*)(ws + (size_t)2 * N * D * 4);          // N*12 f32
    char* p = ws + (size_t)2 * N * D * 4 + (((size_t)N * 12 * 4 + 255) & ~255ull);
    unsigned int* edgeBuf = (unsigned int*)p;  p += (((size_t)E * 4) + 255) & ~255ull;
    int* col_idx     = (int*)p;                p += (((size_t)E * 4) + 255) & ~255ull;
    int* row_ptr     = (int*)p;                p += (((size_t)(N + 1) * 4) + 255) & ~255ull;
    int* blockHist   = (int*)p;                p += ((size_t)NB_EDGE * NBUCK_MAX * 4 + 255) & ~255ull;
    int* bucketTotal = (int*)p;                p += ((size_t)NBUCK_MAX * 4 + 255) & ~255ull;
    int* bucketBase  = (int*)p;                p += ((size_t)(NBUCK_MAX + 1) * 4 + 255) & ~255ull;
    int* goff        = (int*)p;

    // edge grouping (atomic-free global placement) + per-node CSR
    bucket_count<<<NB_EDGE, 512, 0, stream>>>(edst, E, nbuck, blockHist);
    scan_blocks<<<(nbuck * 64 + 255) / 256, 256, 0, stream>>>(blockHist, nbuck, bucketTotal);
    scan_buckets<<<1, 256, 0, stream>>>(bucketTotal, nbuck, bucketBase);
    bucket_place<<<NB_EDGE, 512, 0, stream>>>(esrc, edst, E, nbuck, blockHist, bucketBase, edgeBuf);
    csr_finalize<<<nbuck, 256, 0, stream>>>(edgeBuf, bucketBase, row_ptr, col_idx, N, E);

    // graph offsets
    goff_scan<<<1, 256, 0, stream>>>(gsz, G, goff);

    dim3 ggrid((N + 63) / 64, 2);
    // layer 0
    gemm128<<<ggrid, 256, 0, stream>>>(X, W0, xw, N);
    agg_relu<<<(N * 64 + 255) / 256, 256, 0, stream>>>(xw, row_ptr, col_idx, b0, hbuf, N);
    // layer 1
    gemm128<<<ggrid, 256, 0, stream>>>(hbuf, W1, xw, N);
    agg_relu<<<(N * 64 + 255) / 256, 256, 0, stream>>>(xw, row_ptr, col_idx, b1, hbuf, N);
    // head + readout
    head_sigmoid<<<(N + 255) / 256, 256, 0, stream>>>(hbuf, Wf, bfv, out12, N);
    graph_mean<<<G, 128, 0, stream>>>(out12, goff, gsz, out, G);
}

// Round 4
// 333.456 us; speedup vs baseline: 8.9981x; 1.6642x over previous
//
#include <hip/hip_runtime.h>
#include <math.h>

#define D 128
#define NBUCK_MAX 1024     // runtime nbuck = ceil(N/128) = 782
#define NB_EDGE   128      // edge-chunk blocks for count/placement passes

typedef unsigned short u16;
typedef unsigned int   u32;
typedef __attribute__((ext_vector_type(8))) short short8;   // 8 bf16 = 4 VGPRs (MFMA A/B frag)
typedef __attribute__((ext_vector_type(4))) float f32x4;    // MFMA C/D frag

static __device__ __forceinline__ u16 f32_to_bf16(float f) {
    u32 u = __builtin_bit_cast(u32, f);
    u32 r = (u + 0x7FFFu + ((u >> 16) & 1u)) >> 16;          // RNE
    return (u16)r;
}
static __device__ __forceinline__ u32 pack_bf16x2(float lo, float hi) {
    return (u32)f32_to_bf16(lo) | ((u32)f32_to_bf16(hi) << 16);
}
static __device__ __forceinline__ float bf16lo_to_f32(u32 v) {
    return __builtin_bit_cast(float, v << 16);
}
static __device__ __forceinline__ float bf16hi_to_f32(u32 v) {
    return __builtin_bit_cast(float, v & 0xFFFF0000u);
}

// ---------------- bucketed edge grouping (atomic-free global placement) ----------------

__global__ __launch_bounds__(512) void bucket_count(const int* __restrict__ dst, int E, int nbuck,
                                                    int* __restrict__ blockHist) {
    __shared__ int h[NBUCK_MAX];
    int tid = threadIdx.x;
    for (int i = tid; i < nbuck; i += 512) h[i] = 0;
    __syncthreads();
    int per = (E + NB_EDGE - 1) / NB_EDGE;
    int s = blockIdx.x * per, e = min(E, s + per);
    for (int i = s + tid; i < e; i += 512) atomicAdd(&h[dst[i] >> 7], 1);
    __syncthreads();
    for (int i = tid; i < nbuck; i += 512) blockHist[blockIdx.x * nbuck + i] = h[i];
}

__global__ __launch_bounds__(256) void scan_blocks(int* __restrict__ blockHist, int nbuck,
                                                   int* __restrict__ bucketTotal) {
    int bucket = (blockIdx.x * 256 + threadIdx.x) >> 6;
    int lane = threadIdx.x & 63;
    if (bucket >= nbuck) return;
    int v0 = blockHist[lane * nbuck + bucket];
    int v1 = blockHist[(lane + 64) * nbuck + bucket];
    int i0 = v0;
    #pragma unroll
    for (int off = 1; off < 64; off <<= 1) { int t = __shfl_up(i0, off); if (lane >= off) i0 += t; }
    int tot0 = __shfl(i0, 63);
    int i1 = v1;
    #pragma unroll
    for (int off = 1; off < 64; off <<= 1) { int t = __shfl_up(i1, off); if (lane >= off) i1 += t; }
    i1 += tot0;
    blockHist[lane * nbuck + bucket] = i0 - v0;
    blockHist[(lane + 64) * nbuck + bucket] = i1 - v1;
    if (lane == 63) bucketTotal[bucket] = i1;
}

__global__ __launch_bounds__(256) void scan_buckets(const int* __restrict__ bucketTotal, int nbuck,
                                                    int* __restrict__ bucketBase) {
    __shared__ int wsum[4];
    int tid = threadIdx.x;
    int base = tid * 4;
    int v[4];
    #pragma unroll
    for (int k = 0; k < 4; k++) v[k] = (base + k < nbuck) ? bucketTotal[base + k] : 0;
    int s = v[0] + v[1] + v[2] + v[3];
    int lane = tid & 63;
    int incl = s;
    #pragma unroll
    for (int off = 1; off < 64; off <<= 1) { int t = __shfl_up(incl, off); if (lane >= off) incl += t; }
    int wv = tid >> 6;
    if (lane == 63) wsum[wv] = incl;
    __syncthreads();
    int woff = 0;
    for (int w = 0; w < wv; w++) woff += wsum[w];
    int excl = woff + incl - s;
    int run = excl;
    #pragma unroll
    for (int k = 0; k < 4; k++) {
        if (base + k <= nbuck) bucketBase[base + k] = run;
        run += v[k];
    }
}

__global__ __launch_bounds__(512) void bucket_place(const int* __restrict__ src, const int* __restrict__ dst,
                                                    int E, int nbuck, const int* __restrict__ blockHist,
                                                    const int* __restrict__ bucketBase,
                                                    u32* __restrict__ edgeBuf) {
    __shared__ int cur[NBUCK_MAX];
    int tid = threadIdx.x;
    for (int i = tid; i < nbuck; i += 512)
        cur[i] = bucketBase[i] + blockHist[blockIdx.x * nbuck + i];
    __syncthreads();
    int per = (E + NB_EDGE - 1) / NB_EDGE;
    int s = blockIdx.x * per, e = min(E, s + per);
    for (int i = s + tid; i < e; i += 512) {
        int d = dst[i];
        int b = d >> 7;
        int pos = atomicAdd(&cur[b], 1);
        edgeBuf[pos] = (u32)src[i] | ((u32)(d & 127) << 20);
    }
}

__global__ __launch_bounds__(256) void csr_finalize(const u32* __restrict__ edgeBuf,
                                                    const int* __restrict__ bucketBase,
                                                    int* __restrict__ row_ptr, int* __restrict__ col_idx,
                                                    int N, int E) {
    __shared__ int hist[128];
    __shared__ int cursor[128];
    int b = blockIdx.x;
    int tid = threadIdx.x;
    int start = bucketBase[b], end = bucketBase[b + 1];
    if (tid < 128) hist[tid] = 0;
    __syncthreads();
    for (int i = start + tid; i < end; i += 256)
        atomicAdd(&hist[edgeBuf[i] >> 20], 1);
    __syncthreads();
    if (tid < 64) {
        int v0 = hist[tid * 2], v1 = hist[tid * 2 + 1];
        int s = v0 + v1;
        int incl = s;
        #pragma unroll
        for (int off = 1; off < 64; off <<= 1) { int t = __shfl_up(incl, off); if (tid >= off) incl += t; }
        int excl = incl - s;
        cursor[tid * 2] = excl;
        cursor[tid * 2 + 1] = excl + v0;
        int node = b * 128 + tid * 2;
        if (node < N) row_ptr[node] = start + excl;
        if (node + 1 < N) row_ptr[node + 1] = start + excl + v0;
    }
    __syncthreads();
    for (int i = start + tid; i < end; i += 256) {
        u32 p = edgeBuf[i];
        int pos = atomicAdd(&cursor[p >> 20], 1);
        col_idx[start + pos] = (int)(p & 0xFFFFFu);
    }
    if (b == 0 && tid == 0) row_ptr[N] = E;
}

__global__ __launch_bounds__(256) void goff_scan(const int* __restrict__ gsz, int G, int* __restrict__ goff) {
    __shared__ int wsum[4];
    int tid = threadIdx.x;
    int base = tid * 4;
    int a = base + 0 < G ? gsz[base + 0] : 0;
    int b = base + 1 < G ? gsz[base + 1] : 0;
    int c = base + 2 < G ? gsz[base + 2] : 0;
    int d = base + 3 < G ? gsz[base + 3] : 0;
    int s = a + b + c + d;
    int lane = tid & 63;
    int incl = s;
    #pragma unroll
    for (int off = 1; off < 64; off <<= 1) { int t = __shfl_up(incl, off); if (lane >= off) incl += t; }
    int wv = tid >> 6;
    if (lane == 63) wsum[wv] = incl;
    __syncthreads();
    int woff = 0;
    for (int w = 0; w < wv; w++) woff += wsum[w];
    int excl = woff + incl - s;
    if (base + 0 < G) goff[base + 0] = excl;
    if (base + 1 < G) goff[base + 1] = excl + a;
    if (base + 2 < G) goff[base + 2] = excl + a + b;
    if (base + 3 < G) goff[base + 3] = excl + a + b + c;
}

// ---------------- fp32 -> bf16 cast (8 elems/thread) ----------------
__global__ __launch_bounds__(256) void cast_bf16(const float* __restrict__ X, u16* __restrict__ Xb, int n8) {
    int i = blockIdx.x * 256 + threadIdx.x;
    if (i >= n8) return;
    const float4* x4 = (const float4*)X;
    float4 a = x4[i * 2], b = x4[i * 2 + 1];
    uint4 r;
    r.x = pack_bf16x2(a.x, a.y);
    r.y = pack_bf16x2(a.z, a.w);
    r.z = pack_bf16x2(b.x, b.y);
    r.w = pack_bf16x2(b.z, b.w);
    ((uint4*)Xb)[i] = r;
}

// ---------------- pack W[128][128] fp32 -> B-fragment-ordered bf16 ----------------
// Wp[((nt*4+kt)*64 + lane)*8 + j] = bf16( W[kt*32 + (lane>>4)*8 + j][nt*16 + (lane&15)] )
__global__ __launch_bounds__(256) void pack_W(const float* __restrict__ W, u16* __restrict__ Wp) {
    int idx = blockIdx.x * 256 + threadIdx.x;
    if (idx >= 128 * 128) return;
    int j = idx & 7, lane = (idx >> 3) & 63, kt = (idx >> 9) & 3, nt = idx >> 11;
    int k = kt * 32 + ((lane >> 4) << 3) + j;
    int n = nt * 16 + (lane & 15);
    Wp[idx] = f32_to_bf16(W[k * 128 + n]);
}

// ---------------- MFMA GEMM: outb[N][128] (bf16) = A[N][128] (bf16) @ W (packed bf16) ----------------
// block = 256 thr = 4 waves; wave computes 16 rows x 128 cols; 32 mfma_f32_16x16x32_bf16.
__global__ __launch_bounds__(256) void gemm_mfma(const u16* __restrict__ A, const u16* __restrict__ Wp,
                                                 u16* __restrict__ outb, int N) {
    __shared__ u16 Cs[64 * 136];                     // +8 pad: epilogue writes <=2-way bank alias
    const int tid = threadIdx.x;
    const int wave = tid >> 6;
    const int lane = tid & 63;
    const int quad = lane >> 4;
    const int l16 = lane & 15;
    const int rowt = blockIdx.x * 64 + wave * 16;    // wave's 16-row tile origin
    const int arow = rowt + l16;
    short8 af[4];
    if (arow < N) {
        const u16* ab = A + (size_t)arow * 128 + quad * 8;
        #pragma unroll
        for (int kt = 0; kt < 4; kt++) af[kt] = *(const short8*)(ab + kt * 32);
    } else {
        short8 z = {0, 0, 0, 0, 0, 0, 0, 0};
        #pragma unroll
        for (int kt = 0; kt < 4; kt++) af[kt] = z;
    }
    f32x4 acc[8];
    #pragma unroll
    for (int nt = 0; nt < 8; nt++) acc[nt] = (f32x4){0.f, 0.f, 0.f, 0.f};
    #pragma unroll
    for (int kt = 0; kt < 4; kt++) {
        #pragma unroll
        for (int nt = 0; nt < 8; nt++) {
            short8 bf = *(const short8*)(Wp + ((size_t)(nt * 4 + kt) * 64 + lane) * 8);
            acc[nt] = __builtin_amdgcn_mfma_f32_16x16x32_bf16(af[kt], bf, acc[nt], 0, 0, 0);
        }
    }
    // epilogue: C layout col=lane&15, row=quad*4+reg  ->  LDS transpose -> coalesced bf16 store
    #pragma unroll
    for (int nt = 0; nt < 8; nt++) {
        #pragma unroll
        for (int r = 0; r < 4; r++) {
            int rl = wave * 16 + quad * 4 + r;
            Cs[rl * 136 + nt * 16 + l16] = f32_to_bf16(acc[nt][r]);
        }
    }
    __syncthreads();
    const int row0 = blockIdx.x * 64;
    for (int i = tid; i < 64 * 16; i += 256) {       // 1024 x 16B
        int row = i >> 4, chunk = i & 15;
        int grow = row0 + row;
        if (grow < N)
            *(uint4*)(outb + (size_t)grow * 128 + chunk * 8) =
                *(const uint4*)(Cs + row * 136 + chunk * 8);
    }
}

// ---------------- aggregate (bf16 payload): outh[i] = bf16(relu(xwb[i] + b + sum_j xwb[j])) ----------------
// one wave per node; lane holds 2 dims (1 dword of bf16x2); fp32 accumulate; 8 gathers in flight.
__global__ __launch_bounds__(256) void agg_relu(const u16* __restrict__ xwb, const int* __restrict__ row_ptr,
                                                const int* __restrict__ col_idx, const float* __restrict__ bias,
                                                u16* __restrict__ outh, int N) {
    int wid = (blockIdx.x * 256 + threadIdx.x) >> 6;
    int lane = threadIdx.x & 63;
    if (wid >= N) return;
    const int c2 = lane * 2;
    float2 b = *(const float2*)(bias + c2);
    u32 sv = *(const u32*)(xwb + (size_t)wid * D + c2);
    float2 acc = make_float2(bf16lo_to_f32(sv) + b.x, bf16hi_to_f32(sv) + b.y);
    int start = row_ptr[wid], end = row_ptr[wid + 1];
    for (int e = start; e < end; e += 64) {
        int idx = e + lane;
        int j = (idx < end) ? col_idx[idx] : 0;
        int cnt = min(64, end - e);
        int i = 0;
        for (; i + 7 < cnt; i += 8) {
            int j0 = __shfl(j, i),     j1 = __shfl(j, i + 1);
            int j2 = __shfl(j, i + 2), j3 = __shfl(j, i + 3);
            int j4 = __shfl(j, i + 4), j5 = __shfl(j, i + 5);
            int j6 = __shfl(j, i + 6), j7 = __shfl(j, i + 7);
            u32 v0 = *(const u32*)(xwb + (size_t)j0 * D + c2);
            u32 v1 = *(const u32*)(xwb + (size_t)j1 * D + c2);
            u32 v2 = *(const u32*)(xwb + (size_t)j2 * D + c2);
            u32 v3 = *(const u32*)(xwb + (size_t)j3 * D + c2);
            u32 v4 = *(const u32*)(xwb + (size_t)j4 * D + c2);
            u32 v5 = *(const u32*)(xwb + (size_t)j5 * D + c2);
            u32 v6 = *(const u32*)(xwb + (size_t)j6 * D + c2);
            u32 v7 = *(const u32*)(xwb + (size_t)j7 * D + c2);
            acc.x += ((bf16lo_to_f32(v0) + bf16lo_to_f32(v1)) + (bf16lo_to_f32(v2) + bf16lo_to_f32(v3)))
                   + ((bf16lo_to_f32(v4) + bf16lo_to_f32(v5)) + (bf16lo_to_f32(v6) + bf16lo_to_f32(v7)));
            acc.y += ((bf16hi_to_f32(v0) + bf16hi_to_f32(v1)) + (bf16hi_to_f32(v2) + bf16hi_to_f32(v3)))
                   + ((bf16hi_to_f32(v4) + bf16hi_to_f32(v5)) + (bf16hi_to_f32(v6) + bf16hi_to_f32(v7)));
        }
        for (; i < cnt; i++) {
            int j0 = __shfl(j, i);
            u32 v0 = *(const u32*)(xwb + (size_t)j0 * D + c2);
            acc.x += bf16lo_to_f32(v0);
            acc.y += bf16hi_to_f32(v0);
        }
    }
    acc.x = fmaxf(acc.x, 0.f);
    acc.y = fmaxf(acc.y, 0.f);
    *(u32*)(outh + (size_t)wid * D + c2) = pack_bf16x2(acc.x, acc.y);
}

// ---------------- head: out12[n][12] = sigmoid(h[n] @ Wf + bf), h in bf16 ----------------
__global__ __launch_bounds__(256) void head_sigmoid(const u16* __restrict__ h, const float* __restrict__ Wf,
                                                    const float* __restrict__ bfv, float* __restrict__ out12, int N) {
    __shared__ float Wl[128 * 12];
    __shared__ float bl[12];
    for (int i = threadIdx.x; i < 128 * 12; i += 256) Wl[i] = Wf[i];
    if (threadIdx.x < 12) bl[threadIdx.x] = bfv[threadIdx.x];
    __syncthreads();
    int node = blockIdx.x * 256 + threadIdx.x;
    if (node >= N) return;
    float acc[12];
    #pragma unroll
    for (int t = 0; t < 12; t++) acc[t] = bl[t];
    const u16* hr = h + (size_t)node * D;
    for (int k = 0; k < 128; k += 8) {
        uint4 u = *(const uint4*)(hr + k);
        float x[8];
        x[0] = bf16lo_to_f32(u.x); x[1] = bf16hi_to_f32(u.x);
        x[2] = bf16lo_to_f32(u.y); x[3] = bf16hi_to_f32(u.y);
        x[4] = bf16lo_to_f32(u.z); x[5] = bf16hi_to_f32(u.z);
        x[6] = bf16lo_to_f32(u.w); x[7] = bf16hi_to_f32(u.w);
        #pragma unroll
        for (int kk = 0; kk < 8; kk++) {
            const float* wr = Wl + (k + kk) * 12;
            #pragma unroll
            for (int t = 0; t < 12; t++) acc[t] += x[kk] * wr[t];
        }
    }
    float* o = out12 + (size_t)node * 12;
    #pragma unroll
    for (int t = 0; t < 12; t++) o[t] = 1.f / (1.f + __expf(-acc[t]));
}

// ---------------- per-graph mean ----------------
__global__ __launch_bounds__(128) void graph_mean(const float* __restrict__ out12, const int* __restrict__ goff,
                                                  const int* __restrict__ gsize, float* __restrict__ out, int G) {
    __shared__ float partial[120];
    int g = blockIdx.x;
    int tid = threadIdx.x;
    int start = goff[g];
    int size = gsize[g];
    if (tid < 120) {
        int t = tid % 12, chunk = tid / 12;
        float s = 0.f;
        for (int i = chunk; i < size; i += 10)
            s += out12[(size_t)(start + i) * 12 + t];
        partial[tid] = s;
    }
    __syncthreads();
    if (tid < 12) {
        float tot = 0.f;
        #pragma unroll
        for (int c = 0; c < 10; c++) tot += partial[c * 12 + tid];
        out[g * 12 + tid] = tot / (float)size;
    }
}

// ---------------- launch ----------------

extern "C" void kernel_launch(void* const* d_in, const int* in_sizes, int n_in,
                              void* d_out, int out_size, void* d_ws, size_t ws_size,
                              hipStream_t stream) {
    const float* X   = (const float*)d_in[0];
    const int* edges = (const int*)d_in[1];
    const int* gsz   = (const int*)d_in[2];
    const float* W0  = (const float*)d_in[3];
    const float* b0  = (const float*)d_in[4];
    const float* W1  = (const float*)d_in[5];
    const float* b1  = (const float*)d_in[6];
    const float* Wf  = (const float*)d_in[7];
    const float* bfv = (const float*)d_in[8];
    float* out = (float*)d_out;

    const int N = in_sizes[0] / D;       // 100000
    const int E = in_sizes[1] / 2;       // 1600000
    const int G = in_sizes[2];           // 1000
    const int* esrc = edges;
    const int* edst = edges + E;
    const int nbuck = (N + 127) >> 7;    // 782

    // workspace layout
    char* ws = (char*)d_ws;
    char* p = ws;
    u16* Xb      = (u16*)p;  p += (((size_t)N * D * 2) + 255) & ~255ull;   // 25.6 MB
    u16* xwb     = (u16*)p;  p += (((size_t)N * D * 2) + 255) & ~255ull;   // 25.6 MB
    u16* hb      = (u16*)p;  p += (((size_t)N * D * 2) + 255) & ~255ull;   // 25.6 MB
    float* out12 = (float*)p; p += (((size_t)N * 12 * 4) + 255) & ~255ull; // 4.8 MB
    u16* Wp0     = (u16*)p;  p += ((size_t)128 * 128 * 2 + 255) & ~255ull;
    u16* Wp1     = (u16*)p;  p += ((size_t)128 * 128 * 2 + 255) & ~255ull;
    u32* edgeBuf = (u32*)p;  p += (((size_t)E * 4) + 255) & ~255ull;
    int* col_idx = (int*)p;  p += (((size_t)E * 4) + 255) & ~255ull;
    int* row_ptr = (int*)p;  p += (((size_t)(N + 1) * 4) + 255) & ~255ull;
    int* blockHist   = (int*)p; p += ((size_t)NB_EDGE * NBUCK_MAX * 4 + 255) & ~255ull;
    int* bucketTotal = (int*)p; p += ((size_t)NBUCK_MAX * 4 + 255) & ~255ull;
    int* bucketBase  = (int*)p; p += ((size_t)(NBUCK_MAX + 1) * 4 + 255) & ~255ull;
    int* goff        = (int*)p;

    // edge grouping (atomic-free global placement) + per-node CSR
    bucket_count<<<NB_EDGE, 512, 0, stream>>>(edst, E, nbuck, blockHist);
    scan_blocks<<<(nbuck * 64 + 255) / 256, 256, 0, stream>>>(blockHist, nbuck, bucketTotal);
    scan_buckets<<<1, 256, 0, stream>>>(bucketTotal, nbuck, bucketBase);
    bucket_place<<<NB_EDGE, 512, 0, stream>>>(esrc, edst, E, nbuck, blockHist, bucketBase, edgeBuf);
    csr_finalize<<<nbuck, 256, 0, stream>>>(edgeBuf, bucketBase, row_ptr, col_idx, N, E);

    // casts / packs / graph offsets
    cast_bf16<<<(N * 16 + 255) / 256, 256, 0, stream>>>(X, Xb, N * 16);
    pack_W<<<64, 256, 0, stream>>>(W0, Wp0);
    pack_W<<<64, 256, 0, stream>>>(W1, Wp1);
    goff_scan<<<1, 256, 0, stream>>>(gsz, G, goff);

    const int gemmGrid = (N + 63) / 64;
    // layer 0
    gemm_mfma<<<gemmGrid, 256, 0, stream>>>(Xb, Wp0, xwb, N);
    agg_relu<<<(N * 64 + 255) / 256, 256, 0, stream>>>(xwb, row_ptr, col_idx, b0, hb, N);
    // layer 1
    gemm_mfma<<<gemmGrid, 256, 0, stream>>>(hb, Wp1, xwb, N);
    agg_relu<<<(N * 64 + 255) / 256, 256, 0, stream>>>(xwb, row_ptr, col_idx, b1, hb, N);
    // head + readout
    head_sigmoid<<<(N + 255) / 256, 256, 0, stream>>>(hb, Wf, bfv, out12, N);
    graph_mean<<<G, 128, 0, stream>>>(out12, goff, gsz, out, G);
}

// Round 5
// 314.458 us; speedup vs baseline: 9.5417x; 1.0604x over previous
//
#include <hip/hip_runtime.h>
#include <math.h>

#define D 128
#define NBUCK_MAX 1024     // runtime nbuck = ceil(N/128) = 782
#define NB_EDGE   128      // edge-chunk blocks for count/placement passes

typedef unsigned short u16;
typedef unsigned int   u32;
typedef __attribute__((ext_vector_type(8))) short short8;   // 8 bf16 = 4 VGPRs (MFMA A/B frag)
typedef __attribute__((ext_vector_type(4))) float f32x4;    // MFMA C/D frag

static __device__ __forceinline__ u16 f32_to_bf16(float f) {
    u32 u = __builtin_bit_cast(u32, f);
    u32 r = (u + 0x7FFFu + ((u >> 16) & 1u)) >> 16;          // RNE
    return (u16)r;
}
static __device__ __forceinline__ u32 pack_bf16x2(float lo, float hi) {
    return (u32)f32_to_bf16(lo) | ((u32)f32_to_bf16(hi) << 16);
}
static __device__ __forceinline__ float bf16lo_to_f32(u32 v) {
    return __builtin_bit_cast(float, v << 16);
}
static __device__ __forceinline__ float bf16hi_to_f32(u32 v) {
    return __builtin_bit_cast(float, v & 0xFFFF0000u);
}

// ---------------- bucketed edge grouping (atomic-free global placement) ----------------

__global__ __launch_bounds__(512) void bucket_count(const int* __restrict__ dst, int E, int nbuck,
                                                    int* __restrict__ blockHist) {
    __shared__ int h[NBUCK_MAX];
    int tid = threadIdx.x;
    for (int i = tid; i < nbuck; i += 512) h[i] = 0;
    __syncthreads();
    int per = (E + NB_EDGE - 1) / NB_EDGE;
    int s = blockIdx.x * per, e = min(E, s + per);
    for (int i = s + tid; i < e; i += 512) atomicAdd(&h[dst[i] >> 7], 1);
    __syncthreads();
    for (int i = tid; i < nbuck; i += 512) blockHist[blockIdx.x * nbuck + i] = h[i];
}

__global__ __launch_bounds__(256) void scan_blocks(int* __restrict__ blockHist, int nbuck,
                                                   int* __restrict__ bucketTotal) {
    int bucket = (blockIdx.x * 256 + threadIdx.x) >> 6;
    int lane = threadIdx.x & 63;
    if (bucket >= nbuck) return;
    int v0 = blockHist[lane * nbuck + bucket];
    int v1 = blockHist[(lane + 64) * nbuck + bucket];
    int i0 = v0;
    #pragma unroll
    for (int off = 1; off < 64; off <<= 1) { int t = __shfl_up(i0, off); if (lane >= off) i0 += t; }
    int tot0 = __shfl(i0, 63);
    int i1 = v1;
    #pragma unroll
    for (int off = 1; off < 64; off <<= 1) { int t = __shfl_up(i1, off); if (lane >= off) i1 += t; }
    i1 += tot0;
    blockHist[lane * nbuck + bucket] = i0 - v0;
    blockHist[(lane + 64) * nbuck + bucket] = i1 - v1;
    if (lane == 63) bucketTotal[bucket] = i1;
}

// block 0: exclusive-scan bucket totals -> bucketBase[0..nbuck]; block 1: exclusive-scan graph sizes -> goff
__global__ __launch_bounds__(256) void combo_scan(const int* __restrict__ bucketTotal, int nbuck,
                                                  int* __restrict__ bucketBase,
                                                  const int* __restrict__ gsz, int G,
                                                  int* __restrict__ goff) {
    __shared__ int wsum[4];
    int tid = threadIdx.x;
    int base = tid * 4;
    const int* src = (blockIdx.x == 0) ? bucketTotal : gsz;
    int n = (blockIdx.x == 0) ? nbuck : G;
    int* dstp = (blockIdx.x == 0) ? bucketBase : goff;
    int v[4];
    #pragma unroll
    for (int k = 0; k < 4; k++) v[k] = (base + k < n) ? src[base + k] : 0;
    int s = v[0] + v[1] + v[2] + v[3];
    int lane = tid & 63;
    int incl = s;
    #pragma unroll
    for (int off = 1; off < 64; off <<= 1) { int t = __shfl_up(incl, off); if (lane >= off) incl += t; }
    int wv = tid >> 6;
    if (lane == 63) wsum[wv] = incl;
    __syncthreads();
    int woff = 0;
    for (int w = 0; w < wv; w++) woff += wsum[w];
    int run = woff + incl - s;
    int lim = (blockIdx.x == 0) ? (n + 1) : n;    // bucketBase gets a sentinel
    #pragma unroll
    for (int k = 0; k < 4; k++) {
        if (base + k < lim) dstp[base + k] = run;
        run += v[k];
    }
}

__global__ __launch_bounds__(512) void bucket_place(const int* __restrict__ src, const int* __restrict__ dst,
                                                    int E, int nbuck, const int* __restrict__ blockHist,
                                                    const int* __restrict__ bucketBase,
                                                    u32* __restrict__ edgeBuf) {
    __shared__ int cur[NBUCK_MAX];
    int tid = threadIdx.x;
    for (int i = tid; i < nbuck; i += 512)
        cur[i] = bucketBase[i] + blockHist[blockIdx.x * nbuck + i];
    __syncthreads();
    int per = (E + NB_EDGE - 1) / NB_EDGE;
    int s = blockIdx.x * per, e = min(E, s + per);
    for (int i = s + tid; i < e; i += 512) {
        int d = dst[i];
        int b = d >> 7;
        int pos = atomicAdd(&cur[b], 1);
        edgeBuf[pos] = (u32)src[i] | ((u32)(d & 127) << 20);
    }
}

__global__ __launch_bounds__(256) void csr_finalize(const u32* __restrict__ edgeBuf,
                                                    const int* __restrict__ bucketBase,
                                                    int* __restrict__ row_ptr, int* __restrict__ col_idx,
                                                    int N, int E) {
    __shared__ int hist[128];
    __shared__ int cursor[128];
    int b = blockIdx.x;
    int tid = threadIdx.x;
    int start = bucketBase[b], end = bucketBase[b + 1];
    if (tid < 128) hist[tid] = 0;
    __syncthreads();
    for (int i = start + tid; i < end; i += 256)
        atomicAdd(&hist[edgeBuf[i] >> 20], 1);
    __syncthreads();
    if (tid < 64) {
        int v0 = hist[tid * 2], v1 = hist[tid * 2 + 1];
        int s = v0 + v1;
        int incl = s;
        #pragma unroll
        for (int off = 1; off < 64; off <<= 1) { int t = __shfl_up(incl, off); if (tid >= off) incl += t; }
        int excl = incl - s;
        cursor[tid * 2] = excl;
        cursor[tid * 2 + 1] = excl + v0;
        int node = b * 128 + tid * 2;
        if (node < N) row_ptr[node] = start + excl;
        if (node + 1 < N) row_ptr[node + 1] = start + excl + v0;
    }
    __syncthreads();
    for (int i = start + tid; i < end; i += 256) {
        u32 p = edgeBuf[i];
        int pos = atomicAdd(&cursor[p >> 20], 1);
        col_idx[start + pos] = (int)(p & 0xFFFFFu);
    }
    if (b == 0 && tid == 0) row_ptr[N] = E;
}

// ---------------- pack W0,W1 [128][128] fp32 -> B-fragment-ordered bf16 (one dispatch) ----------------
// Wp[((nt*4+kt)*64 + lane)*8 + j] = bf16( W[kt*32 + (lane>>4)*8 + j][nt*16 + (lane&15)] )
__global__ __launch_bounds__(256) void pack_W2(const float* __restrict__ W0, const float* __restrict__ W1,
                                               u16* __restrict__ Wp0, u16* __restrict__ Wp1) {
    int gidx = blockIdx.x * 256 + threadIdx.x;
    const float* W = (gidx < 128 * 128) ? W0 : W1;
    u16* Wp = (gidx < 128 * 128) ? Wp0 : Wp1;
    int idx = gidx & (128 * 128 - 1);
    int j = idx & 7, lane = (idx >> 3) & 63, kt = (idx >> 9) & 3, nt = idx >> 11;
    int k = kt * 32 + ((lane >> 4) << 3) + j;
    int n = nt * 16 + (lane & 15);
    Wp[idx] = f32_to_bf16(W[k * 128 + n]);
}

// ---------------- MFMA GEMM core (A-frags supplied), 64 rows/block, 4 waves ----------------
static __device__ __forceinline__ void gemm_body(const short8 af[4], const u16* __restrict__ Wp,
                                                 u16* __restrict__ outb, int N,
                                                 int tid, int wave, int lane, int quad, int l16,
                                                 u16* Cs) {
    f32x4 acc[8];
    #pragma unroll
    for (int nt = 0; nt < 8; nt++) acc[nt] = (f32x4){0.f, 0.f, 0.f, 0.f};
    #pragma unroll
    for (int kt = 0; kt < 4; kt++) {
        #pragma unroll
        for (int nt = 0; nt < 8; nt++) {
            short8 bf = *(const short8*)(Wp + ((size_t)(nt * 4 + kt) * 64 + lane) * 8);
            acc[nt] = __builtin_amdgcn_mfma_f32_16x16x32_bf16(af[kt], bf, acc[nt], 0, 0, 0);
        }
    }
    // C layout col=lane&15, row=quad*4+reg -> LDS transpose -> coalesced bf16 store
    #pragma unroll
    for (int nt = 0; nt < 8; nt++) {
        #pragma unroll
        for (int r = 0; r < 4; r++) {
            int rl = wave * 16 + quad * 4 + r;
            Cs[rl * 136 + nt * 16 + l16] = f32_to_bf16(acc[nt][r]);
        }
    }
    __syncthreads();
    const int row0 = blockIdx.x * 64;
    for (int i = tid; i < 64 * 16; i += 256) {
        int row = i >> 4, chunk = i & 15;
        int grow = row0 + row;
        if (grow < N)
            *(uint4*)(outb + (size_t)grow * 128 + chunk * 8) =
                *(const uint4*)(Cs + row * 136 + chunk * 8);
    }
}

// layer-0 variant: reads fp32 A, packs bf16 A-frags in-register (fused cast)
__global__ __launch_bounds__(256) void gemm_mfma_f32(const float* __restrict__ A, const u16* __restrict__ Wp,
                                                     u16* __restrict__ outb, int N) {
    __shared__ u16 Cs[64 * 136];
    const int tid = threadIdx.x;
    const int wave = tid >> 6, lane = tid & 63, quad = lane >> 4, l16 = lane & 15;
    const int arow = blockIdx.x * 64 + wave * 16 + l16;
    union { u32 u[4]; short8 s; } cv;
    short8 af[4];
    if (arow < N) {
        const float* ab = A + (size_t)arow * 128 + quad * 8;
        #pragma unroll
        for (int kt = 0; kt < 4; kt++) {
            float4 x0 = *(const float4*)(ab + kt * 32);
            float4 x1 = *(const float4*)(ab + kt * 32 + 4);
            cv.u[0] = pack_bf16x2(x0.x, x0.y);
            cv.u[1] = pack_bf16x2(x0.z, x0.w);
            cv.u[2] = pack_bf16x2(x1.x, x1.y);
            cv.u[3] = pack_bf16x2(x1.z, x1.w);
            af[kt] = cv.s;
        }
    } else {
        short8 z = {0, 0, 0, 0, 0, 0, 0, 0};
        #pragma unroll
        for (int kt = 0; kt < 4; kt++) af[kt] = z;
    }
    gemm_body(af, Wp, outb, N, tid, wave, lane, quad, l16, Cs);
}

// layer-1 variant: bf16 A
__global__ __launch_bounds__(256) void gemm_mfma(const u16* __restrict__ A, const u16* __restrict__ Wp,
                                                 u16* __restrict__ outb, int N) {
    __shared__ u16 Cs[64 * 136];
    const int tid = threadIdx.x;
    const int wave = tid >> 6, lane = tid & 63, quad = lane >> 4, l16 = lane & 15;
    const int arow = blockIdx.x * 64 + wave * 16 + l16;
    short8 af[4];
    if (arow < N) {
        const u16* ab = A + (size_t)arow * 128 + quad * 8;
        #pragma unroll
        for (int kt = 0; kt < 4; kt++) af[kt] = *(const short8*)(ab + kt * 32);
    } else {
        short8 z = {0, 0, 0, 0, 0, 0, 0, 0};
        #pragma unroll
        for (int kt = 0; kt < 4; kt++) af[kt] = z;
    }
    gemm_body(af, Wp, outb, N, tid, wave, lane, quad, l16, Cs);
}

// ---------------- aggregate: wave per node, 4 rows per vector instruction ----------------
// quarter q = lane>>4 handles edges 4k+q; lane holds 8 dims (uint4 of bf16); fp32 accumulate;
// cross-quarter shfl_xor reduction; quarter 0 stores the 256B row.
static __device__ __forceinline__ void add_row(float* acc, uint4 u, bool v) {
    if (v) {
        acc[0] += bf16lo_to_f32(u.x); acc[1] += bf16hi_to_f32(u.x);
        acc[2] += bf16lo_to_f32(u.y); acc[3] += bf16hi_to_f32(u.y);
        acc[4] += bf16lo_to_f32(u.z); acc[5] += bf16hi_to_f32(u.z);
        acc[6] += bf16lo_to_f32(u.w); acc[7] += bf16hi_to_f32(u.w);
    }
}

__global__ __launch_bounds__(256) void agg_relu(const u16* __restrict__ xwb, const int* __restrict__ row_ptr,
                                                const int* __restrict__ col_idx, const float* __restrict__ bias,
                                                u16* __restrict__ outh, int N) {
    int wid = (blockIdx.x * 256 + threadIdx.x) >> 6;
    int lane = threadIdx.x & 63;
    if (wid >= N) return;
    const int q = lane >> 4;
    const int d8 = (lane & 15) * 8;
    float acc[8] = {0.f, 0.f, 0.f, 0.f, 0.f, 0.f, 0.f, 0.f};
    int start = row_ptr[wid], end = row_ptr[wid + 1];
    for (int e = start; e < end; e += 64) {
        int idx = e + lane;
        int j = (idx < end) ? col_idx[idx] : 0;   // j defaults to 0 (valid row; masked out below)
        int cnt = min(64, end - e);
        for (int i = 0; i < cnt; i += 16) {
            int j0 = __shfl(j, i + q);
            int j1 = __shfl(j, i + 4 + q);
            int j2 = __shfl(j, i + 8 + q);
            int j3 = __shfl(j, i + 12 + q);
            uint4 r0 = *(const uint4*)(xwb + (size_t)j0 * D + d8);
            uint4 r1 = *(const uint4*)(xwb + (size_t)j1 * D + d8);
            uint4 r2 = *(const uint4*)(xwb + (size_t)j2 * D + d8);
            uint4 r3 = *(const uint4*)(xwb + (size_t)j3 * D + d8);
            add_row(acc, r0, (i + q) < cnt);
            add_row(acc, r1, (i + 4 + q) < cnt);
            add_row(acc, r2, (i + 8 + q) < cnt);
            add_row(acc, r3, (i + 12 + q) < cnt);
        }
    }
    #pragma unroll
    for (int t = 0; t < 8; t++) {
        acc[t] += __shfl_xor(acc[t], 16);
        acc[t] += __shfl_xor(acc[t], 32);
    }
    uint4 sv = *(const uint4*)(xwb + (size_t)wid * D + d8);
    float4 ba = *(const float4*)(bias + d8);
    float4 bb = *(const float4*)(bias + d8 + 4);
    float r[8];
    r[0] = fmaxf(acc[0] + bf16lo_to_f32(sv.x) + ba.x, 0.f);
    r[1] = fmaxf(acc[1] + bf16hi_to_f32(sv.x) + ba.y, 0.f);
    r[2] = fmaxf(acc[2] + bf16lo_to_f32(sv.y) + ba.z, 0.f);
    r[3] = fmaxf(acc[3] + bf16hi_to_f32(sv.y) + ba.w, 0.f);
    r[4] = fmaxf(acc[4] + bf16lo_to_f32(sv.z) + bb.x, 0.f);
    r[5] = fmaxf(acc[5] + bf16hi_to_f32(sv.z) + bb.y, 0.f);
    r[6] = fmaxf(acc[6] + bf16lo_to_f32(sv.w) + bb.z, 0.f);
    r[7] = fmaxf(acc[7] + bf16hi_to_f32(sv.w) + bb.w, 0.f);
    if (q == 0) {
        uint4 o;
        o.x = pack_bf16x2(r[0], r[1]);
        o.y = pack_bf16x2(r[2], r[3]);
        o.z = pack_bf16x2(r[4], r[5]);
        o.w = pack_bf16x2(r[6], r[7]);
        *(uint4*)(outh + (size_t)wid * D + d8) = o;
    }
}

// ---------------- fused head + per-graph mean: block per graph ----------------
__global__ __launch_bounds__(128) void head_mean(const u16* __restrict__ h, const float* __restrict__ Wf,
                                                 const float* __restrict__ bfv, const int* __restrict__ goff,
                                                 const int* __restrict__ gsize, float* __restrict__ out, int G) {
    __shared__ float Wl[128 * 12];
    __shared__ float bl[12];
    __shared__ float part[2][12];
    int tid = threadIdx.x;
    for (int i = tid; i < 128 * 12; i += 128) Wl[i] = Wf[i];
    if (tid < 12) bl[tid] = bfv[tid];
    __syncthreads();
    int g = blockIdx.x;
    int start = goff[g];
    int size = gsize[g];
    float sum[12];
    #pragma unroll
    for (int t = 0; t < 12; t++) sum[t] = 0.f;
    for (int n = tid; n < size; n += 128) {
        const u16* hr = h + (size_t)(start + n) * D;
        float acc[12];
        #pragma unroll
        for (int t = 0; t < 12; t++) acc[t] = bl[t];
        for (int k = 0; k < 128; k += 8) {
            uint4 u = *(const uint4*)(hr + k);
            float x[8];
            x[0] = bf16lo_to_f32(u.x); x[1] = bf16hi_to_f32(u.x);
            x[2] = bf16lo_to_f32(u.y); x[3] = bf16hi_to_f32(u.y);
            x[4] = bf16lo_to_f32(u.z); x[5] = bf16hi_to_f32(u.z);
            x[6] = bf16lo_to_f32(u.w); x[7] = bf16hi_to_f32(u.w);
            #pragma unroll
            for (int kk = 0; kk < 8; kk++) {
                const float* wr = Wl + (k + kk) * 12;
                #pragma unroll
                for (int t = 0; t < 12; t++) acc[t] += x[kk] * wr[t];
            }
        }
        #pragma unroll
        for (int t = 0; t < 12; t++) sum[t] += 1.f / (1.f + __expf(-acc[t]));
    }
    int lane = tid & 63, wv = tid >> 6;
    #pragma unroll
    for (int t = 0; t < 12; t++) {
        #pragma unroll
        for (int off = 32; off >= 1; off >>= 1) sum[t] += __shfl_xor(sum[t], off);
    }
    if (lane == 0) {
        #pragma unroll
        for (int t = 0; t < 12; t++) part[wv][t] = sum[t];
    }
    __syncthreads();
    if (tid < 12) out[(size_t)g * 12 + tid] = (part[0][tid] + part[1][tid]) / (float)size;
}

// ---------------- launch ----------------

extern "C" void kernel_launch(void* const* d_in, const int* in_sizes, int n_in,
                              void* d_out, int out_size, void* d_ws, size_t ws_size,
                              hipStream_t stream) {
    const float* X   = (const float*)d_in[0];
    const int* edges = (const int*)d_in[1];
    const int* gsz   = (const int*)d_in[2];
    const float* W0  = (const float*)d_in[3];
    const float* b0  = (const float*)d_in[4];
    const float* W1  = (const float*)d_in[5];
    const float* b1  = (const float*)d_in[6];
    const float* Wf  = (const float*)d_in[7];
    const float* bfv = (const float*)d_in[8];
    float* out = (float*)d_out;

    const int N = in_sizes[0] / D;       // 100000
    const int E = in_sizes[1] / 2;       // 1600000
    const int G = in_sizes[2];           // 1000
    const int* esrc = edges;
    const int* edst = edges + E;
    const int nbuck = (N + 127) >> 7;    // 782

    // workspace layout
    char* ws = (char*)d_ws;
    char* p = ws;
    u16* xwb     = (u16*)p;  p += (((size_t)N * D * 2) + 255) & ~255ull;   // 25.6 MB
    u16* hb      = (u16*)p;  p += (((size_t)N * D * 2) + 255) & ~255ull;   // 25.6 MB
    u16* Wp0     = (u16*)p;  p += ((size_t)128 * 128 * 2 + 255) & ~255ull;
    u16* Wp1     = (u16*)p;  p += ((size_t)128 * 128 * 2 + 255) & ~255ull;
    u32* edgeBuf = (u32*)p;  p += (((size_t)E * 4) + 255) & ~255ull;
    int* col_idx = (int*)p;  p += (((size_t)E * 4) + 255) & ~255ull;
    int* row_ptr = (int*)p;  p += (((size_t)(N + 1) * 4) + 255) & ~255ull;
    int* blockHist   = (int*)p; p += ((size_t)NB_EDGE * NBUCK_MAX * 4 + 255) & ~255ull;
    int* bucketTotal = (int*)p; p += ((size_t)NBUCK_MAX * 4 + 255) & ~255ull;
    int* bucketBase  = (int*)p; p += ((size_t)(NBUCK_MAX + 1) * 4 + 255) & ~255ull;
    int* goff        = (int*)p;

    // edge grouping (atomic-free global placement) + per-node CSR
    bucket_count<<<NB_EDGE, 512, 0, stream>>>(edst, E, nbuck, blockHist);
    scan_blocks<<<(nbuck * 64 + 255) / 256, 256, 0, stream>>>(blockHist, nbuck, bucketTotal);
    combo_scan<<<2, 256, 0, stream>>>(bucketTotal, nbuck, bucketBase, gsz, G, goff);
    bucket_place<<<NB_EDGE, 512, 0, stream>>>(esrc, edst, E, nbuck, blockHist, bucketBase, edgeBuf);
    csr_finalize<<<nbuck, 256, 0, stream>>>(edgeBuf, bucketBase, row_ptr, col_idx, N, E);

    // weight packing (both layers, one dispatch)
    pack_W2<<<128, 256, 0, stream>>>(W0, W1, Wp0, Wp1);

    const int gemmGrid = (N + 63) / 64;
    // layer 0 (fused fp32->bf16 cast in GEMM)
    gemm_mfma_f32<<<gemmGrid, 256, 0, stream>>>(X, Wp0, xwb, N);
    agg_relu<<<(N * 64 + 255) / 256, 256, 0, stream>>>(xwb, row_ptr, col_idx, b0, hb, N);
    // layer 1
    gemm_mfma<<<gemmGrid, 256, 0, stream>>>(hb, Wp1, xwb, N);
    agg_relu<<<(N * 64 + 255) / 256, 256, 0, stream>>>(xwb, row_ptr, col_idx, b1, hb, N);
    // fused head + readout
    head_mean<<<G, 128, 0, stream>>>(hb, Wf, bfv, goff, gsz, out, G);
}

// Round 6
// 309.146 us; speedup vs baseline: 9.7057x; 1.0172x over previous
//
#include <hip/hip_runtime.h>
#include <math.h>

#define D 128
#define NBUCK_MAX 1024     // runtime nbuck = ceil(N/128) = 782
#define NB_EDGE   256      // edge-chunk blocks for count/placement passes

typedef unsigned short u16;
typedef unsigned int   u32;
typedef __attribute__((ext_vector_type(8))) short short8;   // 8 bf16 = 4 VGPRs (MFMA A/B frag)
typedef __attribute__((ext_vector_type(4))) float f32x4;    // MFMA C/D frag

static __device__ __forceinline__ u16 f32_to_bf16(float f) {
    u32 u = __builtin_bit_cast(u32, f);
    u32 r = (u + 0x7FFFu + ((u >> 16) & 1u)) >> 16;          // RNE
    return (u16)r;
}
static __device__ __forceinline__ u32 pack_bf16x2(float lo, float hi) {
    return (u32)f32_to_bf16(lo) | ((u32)f32_to_bf16(hi) << 16);
}
static __device__ __forceinline__ float bf16lo_to_f32(u32 v) {
    return __builtin_bit_cast(float, v << 16);
}
static __device__ __forceinline__ float bf16hi_to_f32(u32 v) {
    return __builtin_bit_cast(float, v & 0xFFFF0000u);
}

// ---------------- bucketed edge grouping (atomic-free global placement) ----------------

__global__ __launch_bounds__(512) void bucket_count(const int* __restrict__ dst, int E, int nbuck,
                                                    int* __restrict__ blockHist) {
    __shared__ int h[NBUCK_MAX];
    int tid = threadIdx.x;
    for (int i = tid; i < nbuck; i += 512) h[i] = 0;
    __syncthreads();
    int per = (E + NB_EDGE - 1) / NB_EDGE;
    int s = blockIdx.x * per, e = min(E, s + per);
    for (int i = s + tid; i < e; i += 512) atomicAdd(&h[dst[i] >> 7], 1);
    __syncthreads();
    for (int i = tid; i < nbuck; i += 512) blockHist[blockIdx.x * nbuck + i] = h[i];
}

// per bucket (one wave): exclusive-scan its NB_EDGE per-block counts in place; emit total.
__global__ __launch_bounds__(256) void scan_blocks(int* __restrict__ blockHist, int nbuck,
                                                   int* __restrict__ bucketTotal) {
    int bucket = (blockIdx.x * 256 + threadIdx.x) >> 6;
    int lane = threadIdx.x & 63;
    if (bucket >= nbuck) return;
    int carry = 0;
    #pragma unroll
    for (int c = 0; c < NB_EDGE / 64; c++) {
        int idx = (c * 64 + lane) * nbuck + bucket;
        int v = blockHist[idx];
        int incl = v;
        #pragma unroll
        for (int off = 1; off < 64; off <<= 1) { int t = __shfl_up(incl, off); if (lane >= off) incl += t; }
        blockHist[idx] = carry + incl - v;
        carry += __shfl(incl, 63);
    }
    if (lane == 0) bucketTotal[bucket] = carry;
}

// block 0: exclusive-scan bucket totals -> bucketBase[0..nbuck]; block 1: exclusive-scan graph sizes -> goff
__global__ __launch_bounds__(256) void combo_scan(const int* __restrict__ bucketTotal, int nbuck,
                                                  int* __restrict__ bucketBase,
                                                  const int* __restrict__ gsz, int G,
                                                  int* __restrict__ goff) {
    __shared__ int wsum[4];
    int tid = threadIdx.x;
    int base = tid * 4;
    const int* src = (blockIdx.x == 0) ? bucketTotal : gsz;
    int n = (blockIdx.x == 0) ? nbuck : G;
    int* dstp = (blockIdx.x == 0) ? bucketBase : goff;
    int v[4];
    #pragma unroll
    for (int k = 0; k < 4; k++) v[k] = (base + k < n) ? src[base + k] : 0;
    int s = v[0] + v[1] + v[2] + v[3];
    int lane = tid & 63;
    int incl = s;
    #pragma unroll
    for (int off = 1; off < 64; off <<= 1) { int t = __shfl_up(incl, off); if (lane >= off) incl += t; }
    int wv = tid >> 6;
    if (lane == 63) wsum[wv] = incl;
    __syncthreads();
    int woff = 0;
    for (int w = 0; w < wv; w++) woff += wsum[w];
    int run = woff + incl - s;
    int lim = (blockIdx.x == 0) ? (n + 1) : n;    // bucketBase gets a sentinel
    #pragma unroll
    for (int k = 0; k < 4; k++) {
        if (base + k < lim) dstp[base + k] = run;
        run += v[k];
    }
}

__global__ __launch_bounds__(512) void bucket_place(const int* __restrict__ src, const int* __restrict__ dst,
                                                    int E, int nbuck, const int* __restrict__ blockHist,
                                                    const int* __restrict__ bucketBase,
                                                    u32* __restrict__ edgeBuf) {
    __shared__ int cur[NBUCK_MAX];
    int tid = threadIdx.x;
    for (int i = tid; i < nbuck; i += 512)
        cur[i] = bucketBase[i] + blockHist[blockIdx.x * nbuck + i];
    __syncthreads();
    int per = (E + NB_EDGE - 1) / NB_EDGE;
    int s = blockIdx.x * per, e = min(E, s + per);
    for (int i = s + tid; i < e; i += 512) {
        int d = dst[i];
        int b = d >> 7;
        int pos = atomicAdd(&cur[b], 1);
        edgeBuf[pos] = (u32)src[i] | ((u32)(d & 127) << 20);
    }
}

__global__ __launch_bounds__(256) void csr_finalize(const u32* __restrict__ edgeBuf,
                                                    const int* __restrict__ bucketBase,
                                                    int* __restrict__ row_ptr, int* __restrict__ col_idx,
                                                    int N, int E) {
    __shared__ int hist[128];
    __shared__ int cursor[128];
    int b = blockIdx.x;
    int tid = threadIdx.x;
    int start = bucketBase[b], end = bucketBase[b + 1];
    if (tid < 128) hist[tid] = 0;
    __syncthreads();
    for (int i = start + tid; i < end; i += 256)
        atomicAdd(&hist[edgeBuf[i] >> 20], 1);
    __syncthreads();
    if (tid < 64) {
        int v0 = hist[tid * 2], v1 = hist[tid * 2 + 1];
        int s = v0 + v1;
        int incl = s;
        #pragma unroll
        for (int off = 1; off < 64; off <<= 1) { int t = __shfl_up(incl, off); if (tid >= off) incl += t; }
        int excl = incl - s;
        cursor[tid * 2] = excl;
        cursor[tid * 2 + 1] = excl + v0;
        int node = b * 128 + tid * 2;
        if (node < N) row_ptr[node] = start + excl;
        if (node + 1 < N) row_ptr[node + 1] = start + excl + v0;
    }
    __syncthreads();
    for (int i = start + tid; i < end; i += 256) {
        u32 p = edgeBuf[i];
        int pos = atomicAdd(&cursor[p >> 20], 1);
        col_idx[start + pos] = (int)(p & 0xFFFFFu);
    }
    if (b == 0 && tid == 0) row_ptr[N] = E;
}

// ---------------- pack W0,W1 [128][128] fp32 -> B-fragment-ordered bf16 (one dispatch) ----------------
// Wp[((nt*4+kt)*64 + lane)*8 + j] = bf16( W[kt*32 + (lane>>4)*8 + j][nt*16 + (lane&15)] )
__global__ __launch_bounds__(256) void pack_W2(const float* __restrict__ W0, const float* __restrict__ W1,
                                               u16* __restrict__ Wp0, u16* __restrict__ Wp1) {
    int gidx = blockIdx.x * 256 + threadIdx.x;
    const float* W = (gidx < 128 * 128) ? W0 : W1;
    u16* Wp = (gidx < 128 * 128) ? Wp0 : Wp1;
    int idx = gidx & (128 * 128 - 1);
    int j = idx & 7, lane = (idx >> 3) & 63, kt = (idx >> 9) & 3, nt = idx >> 11;
    int k = kt * 32 + ((lane >> 4) << 3) + j;
    int n = nt * 16 + (lane & 15);
    Wp[idx] = f32_to_bf16(W[k * 128 + n]);
}

// ---------------- MFMA GEMM core (A-frags supplied), 64 rows/block, 4 waves ----------------
// Stores rows [row0, row0+64) clipped to <= N: row N is the shared zero row (A-frags were zero).
static __device__ __forceinline__ void gemm_body(const short8 af[4], const u16* __restrict__ Wp,
                                                 u16* __restrict__ outb, int N,
                                                 int tid, int wave, int lane, int quad, int l16,
                                                 u16* Cs) {
    f32x4 acc[8];
    #pragma unroll
    for (int nt = 0; nt < 8; nt++) acc[nt] = (f32x4){0.f, 0.f, 0.f, 0.f};
    #pragma unroll
    for (int kt = 0; kt < 4; kt++) {
        #pragma unroll
        for (int nt = 0; nt < 8; nt++) {
            short8 bf = *(const short8*)(Wp + ((size_t)(nt * 4 + kt) * 64 + lane) * 8);
            acc[nt] = __builtin_amdgcn_mfma_f32_16x16x32_bf16(af[kt], bf, acc[nt], 0, 0, 0);
        }
    }
    // C layout col=lane&15, row=quad*4+reg -> LDS transpose -> coalesced bf16 store
    #pragma unroll
    for (int nt = 0; nt < 8; nt++) {
        #pragma unroll
        for (int r = 0; r < 4; r++) {
            int rl = wave * 16 + quad * 4 + r;
            Cs[rl * 136 + nt * 16 + l16] = f32_to_bf16(acc[nt][r]);
        }
    }
    __syncthreads();
    const int row0 = blockIdx.x * 64;
    for (int i = tid; i < 64 * 16; i += 256) {
        int row = i >> 4, chunk = i & 15;
        int grow = row0 + row;
        if (grow <= N)      // row N = zero pad row for agg tail lanes
            *(uint4*)(outb + (size_t)grow * 128 + chunk * 8) =
                *(const uint4*)(Cs + row * 136 + chunk * 8);
    }
}

// layer-0 variant: reads fp32 A, packs bf16 A-frags in-register (fused cast)
__global__ __launch_bounds__(256) void gemm_mfma_f32(const float* __restrict__ A, const u16* __restrict__ Wp,
                                                     u16* __restrict__ outb, int N) {
    __shared__ u16 Cs[64 * 136];
    const int tid = threadIdx.x;
    const int wave = tid >> 6, lane = tid & 63, quad = lane >> 4, l16 = lane & 15;
    const int arow = blockIdx.x * 64 + wave * 16 + l16;
    union { u32 u[4]; short8 s; } cv;
    short8 af[4];
    if (arow < N) {
        const float* ab = A + (size_t)arow * 128 + quad * 8;
        #pragma unroll
        for (int kt = 0; kt < 4; kt++) {
            float4 x0 = *(const float4*)(ab + kt * 32);
            float4 x1 = *(const float4*)(ab + kt * 32 + 4);
            cv.u[0] = pack_bf16x2(x0.x, x0.y);
            cv.u[1] = pack_bf16x2(x0.z, x0.w);
            cv.u[2] = pack_bf16x2(x1.x, x1.y);
            cv.u[3] = pack_bf16x2(x1.z, x1.w);
            af[kt] = cv.s;
        }
    } else {
        short8 z = {0, 0, 0, 0, 0, 0, 0, 0};
        #pragma unroll
        for (int kt = 0; kt < 4; kt++) af[kt] = z;
    }
    gemm_body(af, Wp, outb, N, tid, wave, lane, quad, l16, Cs);
}

// layer-1 variant: bf16 A
__global__ __launch_bounds__(256) void gemm_mfma(const u16* __restrict__ A, const u16* __restrict__ Wp,
                                                 u16* __restrict__ outb, int N) {
    __shared__ u16 Cs[64 * 136];
    const int tid = threadIdx.x;
    const int wave = tid >> 6, lane = tid & 63, quad = lane >> 4, l16 = lane & 15;
    const int arow = blockIdx.x * 64 + wave * 16 + l16;
    short8 af[4];
    if (arow < N) {
        const u16* ab = A + (size_t)arow * 128 + quad * 8;
        #pragma unroll
        for (int kt = 0; kt < 4; kt++) af[kt] = *(const short8*)(ab + kt * 32);
    } else {
        short8 z = {0, 0, 0, 0, 0, 0, 0, 0};
        #pragma unroll
        for (int kt = 0; kt < 4; kt++) af[kt] = z;
    }
    gemm_body(af, Wp, outb, N, tid, wave, lane, quad, l16, Cs);
}

// ---------------- aggregate: wave per node, 4 rows per vector instruction ----------------
// quarter q = lane>>4 handles edges 4k+q; lane holds 8 dims (uint4 of bf16); fp32 accumulate;
// tail lanes gather the zero row (index N) — no masking; cross-quarter shfl_xor reduce; q0 stores.
static __device__ __forceinline__ void add_row(float* acc, uint4 u) {
    acc[0] += bf16lo_to_f32(u.x); acc[1] += bf16hi_to_f32(u.x);
    acc[2] += bf16lo_to_f32(u.y); acc[3] += bf16hi_to_f32(u.y);
    acc[4] += bf16lo_to_f32(u.z); acc[5] += bf16hi_to_f32(u.z);
    acc[6] += bf16lo_to_f32(u.w); acc[7] += bf16hi_to_f32(u.w);
}

__global__ __launch_bounds__(256) void agg_relu(const u16* __restrict__ xwb, const int* __restrict__ row_ptr,
                                                const int* __restrict__ col_idx, const float* __restrict__ bias,
                                                u16* __restrict__ outh, int N) {
    int wid = (blockIdx.x * 256 + threadIdx.x) >> 6;
    int lane = threadIdx.x & 63;
    if (wid >= N) return;
    const int q = lane >> 4;
    const int d8 = (lane & 15) * 8;
    float acc[8] = {0.f, 0.f, 0.f, 0.f, 0.f, 0.f, 0.f, 0.f};
    int start = row_ptr[wid], end = row_ptr[wid + 1];
    for (int e = start; e < end; e += 64) {
        int idx = e + lane;
        int j = (idx < end) ? col_idx[idx] : N;   // tail -> shared zero row
        int cnt = min(64, end - e);
        for (int i = 0; i < cnt; i += 16) {
            int j0 = __shfl(j, i + q);
            int j1 = __shfl(j, i + 4 + q);
            int j2 = __shfl(j, i + 8 + q);
            int j3 = __shfl(j, i + 12 + q);
            uint4 r0 = *(const uint4*)(xwb + (size_t)j0 * D + d8);
            uint4 r1 = *(const uint4*)(xwb + (size_t)j1 * D + d8);
            uint4 r2 = *(const uint4*)(xwb + (size_t)j2 * D + d8);
            uint4 r3 = *(const uint4*)(xwb + (size_t)j3 * D + d8);
            add_row(acc, r0);
            add_row(acc, r1);
            add_row(acc, r2);
            add_row(acc, r3);
        }
    }
    #pragma unroll
    for (int t = 0; t < 8; t++) {
        acc[t] += __shfl_xor(acc[t], 16);
        acc[t] += __shfl_xor(acc[t], 32);
    }
    uint4 sv = *(const uint4*)(xwb + (size_t)wid * D + d8);
    float4 ba = *(const float4*)(bias + d8);
    float4 bb = *(const float4*)(bias + d8 + 4);
    float r[8];
    r[0] = fmaxf(acc[0] + bf16lo_to_f32(sv.x) + ba.x, 0.f);
    r[1] = fmaxf(acc[1] + bf16hi_to_f32(sv.x) + ba.y, 0.f);
    r[2] = fmaxf(acc[2] + bf16lo_to_f32(sv.y) + ba.z, 0.f);
    r[3] = fmaxf(acc[3] + bf16hi_to_f32(sv.y) + ba.w, 0.f);
    r[4] = fmaxf(acc[4] + bf16lo_to_f32(sv.z) + bb.x, 0.f);
    r[5] = fmaxf(acc[5] + bf16hi_to_f32(sv.z) + bb.y, 0.f);
    r[6] = fmaxf(acc[6] + bf16lo_to_f32(sv.w) + bb.z, 0.f);
    r[7] = fmaxf(acc[7] + bf16hi_to_f32(sv.w) + bb.w, 0.f);
    if (q == 0) {
        uint4 o;
        o.x = pack_bf16x2(r[0], r[1]);
        o.y = pack_bf16x2(r[2], r[3]);
        o.z = pack_bf16x2(r[4], r[5]);
        o.w = pack_bf16x2(r[6], r[7]);
        *(uint4*)(outh + (size_t)wid * D + d8) = o;
    }
}

// ---------------- fused head + per-graph mean: block per graph ----------------
__global__ __launch_bounds__(128) void head_mean(const u16* __restrict__ h, const float* __restrict__ Wf,
                                                 const float* __restrict__ bfv, const int* __restrict__ goff,
                                                 const int* __restrict__ gsize, float* __restrict__ out, int G) {
    __shared__ float Wl[128 * 12];
    __shared__ float bl[12];
    __shared__ float part[2][12];
    int tid = threadIdx.x;
    for (int i = tid; i < 128 * 12; i += 128) Wl[i] = Wf[i];
    if (tid < 12) bl[tid] = bfv[tid];
    __syncthreads();
    int g = blockIdx.x;
    int start = goff[g];
    int size = gsize[g];
    float sum[12];
    #pragma unroll
    for (int t = 0; t < 12; t++) sum[t] = 0.f;
    for (int n = tid; n < size; n += 128) {
        const u16* hr = h + (size_t)(start + n) * D;
        float acc[12];
        #pragma unroll
        for (int t = 0; t < 12; t++) acc[t] = bl[t];
        for (int k = 0; k < 128; k += 8) {
            uint4 u = *(const uint4*)(hr + k);
            float x[8];
            x[0] = bf16lo_to_f32(u.x); x[1] = bf16hi_to_f32(u.x);
            x[2] = bf16lo_to_f32(u.y); x[3] = bf16hi_to_f32(u.y);
            x[4] = bf16lo_to_f32(u.z); x[5] = bf16hi_to_f32(u.z);
            x[6] = bf16lo_to_f32(u.w); x[7] = bf16hi_to_f32(u.w);
            #pragma unroll
            for (int kk = 0; kk < 8; kk++) {
                const float* wr = Wl + (k + kk) * 12;
                #pragma unroll
                for (int t = 0; t < 12; t++) acc[t] += x[kk] * wr[t];
            }
        }
        #pragma unroll
        for (int t = 0; t < 12; t++) sum[t] += 1.f / (1.f + __expf(-acc[t]));
    }
    int lane = tid & 63, wv = tid >> 6;
    #pragma unroll
    for (int t = 0; t < 12; t++) {
        #pragma unroll
        for (int off = 32; off >= 1; off >>= 1) sum[t] += __shfl_xor(sum[t], off);
    }
    if (lane == 0) {
        #pragma unroll
        for (int t = 0; t < 12; t++) part[wv][t] = sum[t];
    }
    __syncthreads();
    if (tid < 12) out[(size_t)g * 12 + tid] = (part[0][tid] + part[1][tid]) / (float)size;
}

// ---------------- launch ----------------

extern "C" void kernel_launch(void* const* d_in, const int* in_sizes, int n_in,
                              void* d_out, int out_size, void* d_ws, size_t ws_size,
                              hipStream_t stream) {
    const float* X   = (const float*)d_in[0];
    const int* edges = (const int*)d_in[1];
    const int* gsz   = (const int*)d_in[2];
    const float* W0  = (const float*)d_in[3];
    const float* b0  = (const float*)d_in[4];
    const float* W1  = (const float*)d_in[5];
    const float* b1  = (const float*)d_in[6];
    const float* Wf  = (const float*)d_in[7];
    const float* bfv = (const float*)d_in[8];
    float* out = (float*)d_out;

    const int N = in_sizes[0] / D;       // 100000
    const int E = in_sizes[1] / 2;       // 1600000
    const int G = in_sizes[2];           // 1000
    const int* esrc = edges;
    const int* edst = edges + E;
    const int nbuck = (N + 127) >> 7;    // 782

    // workspace layout (xwb gets N+64 rows: row N is the zero pad row)
    char* ws = (char*)d_ws;
    char* p = ws;
    u16* xwb     = (u16*)p;  p += (((size_t)(N + 64) * D * 2) + 255) & ~255ull;
    u16* hb      = (u16*)p;  p += (((size_t)(N + 64) * D * 2) + 255) & ~255ull;
    u16* Wp0     = (u16*)p;  p += ((size_t)128 * 128 * 2 + 255) & ~255ull;
    u16* Wp1     = (u16*)p;  p += ((size_t)128 * 128 * 2 + 255) & ~255ull;
    u32* edgeBuf = (u32*)p;  p += (((size_t)E * 4) + 255) & ~255ull;
    int* col_idx = (int*)p;  p += (((size_t)E * 4) + 255) & ~255ull;
    int* row_ptr = (int*)p;  p += (((size_t)(N + 1) * 4) + 255) & ~255ull;
    int* blockHist   = (int*)p; p += ((size_t)NB_EDGE * NBUCK_MAX * 4 + 255) & ~255ull;
    int* bucketTotal = (int*)p; p += ((size_t)NBUCK_MAX * 4 + 255) & ~255ull;
    int* bucketBase  = (int*)p; p += ((size_t)(NBUCK_MAX + 1) * 4 + 255) & ~255ull;
    int* goff        = (int*)p;

    // edge grouping (atomic-free global placement) + per-node CSR
    bucket_count<<<NB_EDGE, 512, 0, stream>>>(edst, E, nbuck, blockHist);
    scan_blocks<<<(nbuck * 64 + 255) / 256, 256, 0, stream>>>(blockHist, nbuck, bucketTotal);
    combo_scan<<<2, 256, 0, stream>>>(bucketTotal, nbuck, bucketBase, gsz, G, goff);
    bucket_place<<<NB_EDGE, 512, 0, stream>>>(esrc, edst, E, nbuck, blockHist, bucketBase, edgeBuf);
    csr_finalize<<<nbuck, 256, 0, stream>>>(edgeBuf, bucketBase, row_ptr, col_idx, N, E);

    // weight packing (both layers, one dispatch)
    pack_W2<<<128, 256, 0, stream>>>(W0, W1, Wp0, Wp1);

    const int gemmGrid = (N + 63) / 64;
    // layer 0 (fused fp32->bf16 cast in GEMM)
    gemm_mfma_f32<<<gemmGrid, 256, 0, stream>>>(X, Wp0, xwb, N);
    agg_relu<<<(N * 64 + 255) / 256, 256, 0, stream>>>(xwb, row_ptr, col_idx, b0, hb, N);
    // layer 1
    gemm_mfma<<<gemmGrid, 256, 0, stream>>>(hb, Wp1, xwb, N);
    agg_relu<<<(N * 64 + 255) / 256, 256, 0, stream>>>(xwb, row_ptr, col_idx, b1, hb, N);
    // fused head + readout
    head_mean<<<G, 128, 0, stream>>>(hb, Wf, bfv, goff, gsz, out, G);
}